// Round 11
// baseline (771.146 us; speedup 1.0000x reference)
//
#include <hip/hip_runtime.h>
#include <math.h>

typedef short short8 __attribute__((ext_vector_type(8)));
typedef float f32x4 __attribute__((ext_vector_type(4)));
typedef unsigned short us4 __attribute__((ext_vector_type(4)));

#define MAXDEG 32
#define GF_BIAS   1
#define GF_CSHIFT 2
#define GF_ALPHA  4
#define GF_BF16   8
#define NFRAG 18432   // 9 nt-tiles * 4 kt * 64 lanes * 8 bf16

__device__ __forceinline__ unsigned short f2bf(float f) {  // RNE f32->bf16
  unsigned u = __float_as_uint(f);
  u += 0x7FFF + ((u >> 16) & 1);
  return (unsigned short)(u >> 16);
}
__device__ __forceinline__ float bf2f(unsigned short s) { return __uint_as_float(((unsigned)s) << 16); }
__device__ __forceinline__ float lrelu(float v) { return v > 0.f ? v : 0.2f * v; }

// ---------------- CSR slot-scatter (3 relations) + fused geo reduce, 4-way ILP ------
__global__ __launch_bounds__(256) void k_scatter3(
    const int* __restrict__ ei0, const int* __restrict__ ei1, const int* __restrict__ ei2,
    int* __restrict__ cur,
    int* __restrict__ s0, int* __restrict__ s1, int* __restrict__ s2,
    const float* __restrict__ pos, float* __restrict__ gsum, int E, int N) {
  __shared__ float part[4];
  const int T4 = gridDim.x * 256;
  const int t = blockIdx.x * 256 + threadIdx.x;
  float d = 0.f;
  #pragma unroll
  for (int k = 0; k < 4; ++k) {
    const int idx = t + k * T4;
    if (idx >= 3 * E) continue;
    int rel, e;
    if (idx < E)          { rel = 0; e = idx; }
    else if (idx < 2 * E) { rel = 1; e = idx - E; }
    else                  { rel = 2; e = idx - 2 * E; }
    const int* ei = (rel == 0) ? ei0 : (rel == 1) ? ei1 : ei2;
    int* srcs     = (rel == 0) ? s0  : (rel == 1) ? s1  : s2;
    const int r = ei[e];
    const int c = ei[E + e];
    const int slot = atomicAdd(&cur[rel * N + c], 1);
    if (slot < MAXDEG) srcs[(size_t)c * MAXDEG + slot] = r;
    if (rel == 2) {
      const float dx = pos[3*r]   - pos[3*c];
      const float dy = pos[3*r+1] - pos[3*c+1];
      const float dz = pos[3*r+2] - pos[3*c+2];
      d += sqrtf(dx*dx + dy*dy + dz*dz);
    }
  }
  #pragma unroll
  for (int o = 32; o; o >>= 1) d += __shfl_down(d, o);
  if ((threadIdx.x & 63) == 0) part[threadIdx.x >> 6] = d;
  __syncthreads();
  if (threadIdx.x == 0) {
    const float s = part[0] + part[1] + part[2] + part[3];
    if (s != 0.f) atomicAdd(gsum, s);
  }
}

// ---------------- weight prep: bf16 hi/lo fragment images + alpha cols + colsums ----
struct PrepArgs {
  const float* W[9];
  const float* as_[9];
  const float* ad_[9];
  unsigned short* hi[9];
  unsigned short* lo[9];
  float* csum[9];
  int fh[9];   // 0 = no alpha cols
};

__global__ __launch_bounds__(256) void k_prep(PrepArgs p) {
  const int s = blockIdx.x;
  const int t = threadIdx.x;
  const float* W = p.W[s];
  const int fh = p.fh[s];
  __shared__ float Ws[128 * 129];
  __shared__ float alpha[128 * 8];
  {
    const f32x4* src = (const f32x4*)W;
    for (int i = t; i < 4096; i += 256) {     // 16384 floats, coalesced
      const f32x4 v = src[i];
      const int row = i >> 5;
      const int col = (i & 31) * 4;
      float* dst = &Ws[row * 129 + col];
      dst[0] = v[0]; dst[1] = v[1]; dst[2] = v[2]; dst[3] = v[3];
    }
  }
  __syncthreads();
  if (t < 128) {
    #pragma unroll
    for (int a = 0; a < 8; ++a) alpha[t * 8 + a] = 0.f;
    if (fh) {
      const int nh = 128 / fh;
      for (int h = 0; h < nh; ++h) {
        float s1 = 0.f, s2 = 0.f;
        for (int c = 0; c < fh; ++c) {
          const float w = Ws[t * 129 + h * fh + c];
          s1 += w * p.as_[s][h * fh + c];
          s2 += w * p.ad_[s][h * fh + c];
        }
        alpha[t * 8 + h] = s1;
        alpha[t * 8 + 4 + h] = s2;
      }
    }
  }
  __syncthreads();
  for (int idx = t; idx < NFRAG; idx += 256) {
    const int j = idx & 7, lane = (idx >> 3) & 63, kt = (idx >> 9) & 3, nt = idx >> 11;
    const int k = kt * 32 + (lane >> 4) * 8 + j;
    const int col = nt * 16 + (lane & 15);
    float w;
    if (col < 128) w = Ws[k * 129 + col];
    else if (col < 136) w = alpha[k * 8 + (col - 128)];
    else w = 0.f;
    const unsigned short h = f2bf(w);
    p.hi[s][idx] = h;
    p.lo[s][idx] = f2bf(w - bf2f(h));
  }
  if (t < 136) {
    float cs = 0.f;
    if (t < 128) for (int k = 0; k < 128; ++k) cs += Ws[k * 129 + t];
    else         for (int k = 0; k < 128; ++k) cs += alpha[k * 8 + (t - 128)];
    p.csum[s][t] = cs;
  }
}

// ---------------- split-bf16 MFMA GEMM: C[n,128] = A[n,128] @ W[128,128] -------------
// LDS-staged weights (proven best). GF_BF16: write C as bf16 for gather consumers.
__global__ __launch_bounds__(256, 2) void k_gmm(
    const float* __restrict__ A, const unsigned short* __restrict__ Whi,
    const unsigned short* __restrict__ Wlo, const float* __restrict__ csum,
    const float* __restrict__ bias, float* __restrict__ C,
    float* __restrict__ aS, float* __restrict__ aD,
    const float* __restrict__ gsum, float gscale,
    int n, int npad, int flags)
{
  __shared__ unsigned short shi[NFRAG];
  __shared__ unsigned short slo[NFRAG];
  {
    const f32x4* srch = (const f32x4*)Whi;
    const f32x4* srcl = (const f32x4*)Wlo;
    f32x4* dsth = (f32x4*)shi;
    f32x4* dstl = (f32x4*)slo;
    for (int i = threadIdx.x; i < NFRAG / 8; i += 256) { dsth[i] = srch[i]; dstl[i] = srcl[i]; }
  }
  __syncthreads();

  const int wave = threadIdx.x >> 6, lane = threadIdx.x & 63;
  const int m = lane & 15, kq = lane >> 4;
  const float cb = (flags & GF_CSHIFT) ? gscale * gsum[0] : 0.f;

  for (int rb = blockIdx.x * 128; rb < npad; rb += gridDim.x * 128) {
    const int rw = rb + wave * 32;
    short8 ah[2][4], al[2][4];
    #pragma unroll
    for (int sub = 0; sub < 2; ++sub) {
      const int row = rw + sub * 16 + m;
      const bool ok = row < n;
      const float* ap = A + (size_t)row * 128 + kq * 8;
      #pragma unroll
      for (int kt = 0; kt < 4; ++kt) {
        f32x4 x0 = {0.f, 0.f, 0.f, 0.f}, x1 = {0.f, 0.f, 0.f, 0.f};
        if (ok) { x0 = *(const f32x4*)(ap + kt * 32); x1 = *(const f32x4*)(ap + kt * 32 + 4); }
        #pragma unroll
        for (int j = 0; j < 4; ++j) {
          unsigned short h0 = f2bf(x0[j]);
          ah[sub][kt][j] = (short)h0;
          al[sub][kt][j] = (short)f2bf(x0[j] - bf2f(h0));
          unsigned short h1 = f2bf(x1[j]);
          ah[sub][kt][4 + j] = (short)h1;
          al[sub][kt][4 + j] = (short)f2bf(x1[j] - bf2f(h1));
        }
      }
    }
    f32x4 acc[2][9];
    #pragma unroll
    for (int sub = 0; sub < 2; ++sub)
      #pragma unroll
      for (int nt = 0; nt < 9; ++nt) acc[sub][nt] = f32x4{0.f, 0.f, 0.f, 0.f};

    #pragma unroll
    for (int nt = 0; nt < 9; ++nt) {
      #pragma unroll
      for (int kt = 0; kt < 4; ++kt) {
        const int fo = ((nt * 4 + kt) * 64 + lane) * 8;
        const short8 bh = *(const short8*)&shi[fo];
        const short8 bl = *(const short8*)&slo[fo];
        #pragma unroll
        for (int sub = 0; sub < 2; ++sub) {
          acc[sub][nt] = __builtin_amdgcn_mfma_f32_16x16x32_bf16(ah[sub][kt], bh, acc[sub][nt], 0, 0, 0);
          acc[sub][nt] = __builtin_amdgcn_mfma_f32_16x16x32_bf16(al[sub][kt], bh, acc[sub][nt], 0, 0, 0);
          acc[sub][nt] = __builtin_amdgcn_mfma_f32_16x16x32_bf16(ah[sub][kt], bl, acc[sub][nt], 0, 0, 0);
        }
      }
    }
    // epilogue: C/D layout col = lane&15, row = (lane>>4)*4 + r
    #pragma unroll
    for (int sub = 0; sub < 2; ++sub) {
      const int rbase = rw + sub * 16 + kq * 4;
      #pragma unroll
      for (int nt = 0; nt < 8; ++nt) {
        const int col = nt * 16 + m;
        const float cs = (flags & GF_CSHIFT) ? cb * csum[col] : 0.f;
        const float bb = (flags & GF_BIAS) ? bias[col] : 0.f;
        if (flags & GF_BF16) {
          unsigned short* Cb = (unsigned short*)C;
          #pragma unroll
          for (int r = 0; r < 4; ++r)
            Cb[(size_t)(rbase + r) * 128 + col] = f2bf(acc[sub][nt][r] + cs);
        } else {
          #pragma unroll
          for (int r = 0; r < 4; ++r)
            C[(size_t)(rbase + r) * 128 + col] = acc[sub][nt][r] + cs + bb;
        }
      }
      if ((flags & GF_ALPHA) && m < 8) {
        const float cs = (flags & GF_CSHIFT) ? cb * csum[128 + m] : 0.f;
        #pragma unroll
        for (int r = 0; r < 4; ++r) {
          const float v = acc[sub][8][r] + cs;
          const int row = rbase + r;
          if (m < 4) aS[(size_t)row * 4 + m] = v;
          else       aD[(size_t)row * 4 + (m - 4)] = v;
        }
      }
    }
  }
}

// ---------------- GAT conv (bf16 h rows): 2 dst nodes/wave, 32 lanes each ----------
// mode: 0 = write, 1 = accumulate, 2 = accumulate + relu   [R9-proven form]
__global__ __launch_bounds__(256) void k_conv(
    const unsigned short* __restrict__ hb, const float* __restrict__ aS,
    const float* __restrict__ aD,
    const int* __restrict__ srcs, const int* __restrict__ cnt,
    const float* __restrict__ bias, float* __restrict__ out,
    int fh_shift, int mode, int n)
{
  __shared__ int   ssh[4][2][32];
  __shared__ float wsh[4][2][32][4];
  const int wv = threadIdx.x >> 6;
  const int lane = threadIdx.x & 63;
  const int hf = lane >> 5;
  const int l  = lane & 31;
  const int i = blockIdx.x * 8 + wv * 2 + hf;
  const bool iok = i < n;
  const int ipad = iok ? i : 0;
  const int c0 = l * 4;
  const int hd = c0 >> fh_shift;

  int deg = 0;
  if (iok) { deg = cnt[i]; if (deg > MAXDEG) deg = MAXDEG; }
  const int* sp = srcs + (size_t)ipad * MAXDEG;

  const bool valid = l < deg;
  int s = ipad;
  if (valid) s = sp[l];

  f32x4 ad4 = f32x4{0.f, 0.f, 0.f, 0.f}, asi = f32x4{0.f, 0.f, 0.f, 0.f};
  if (iok) {
    ad4 = *(const f32x4*)(aD + (size_t)i * 4);
    asi = *(const f32x4*)(aS + (size_t)i * 4);
  }
  f32x4 as4 = f32x4{0.f, 0.f, 0.f, 0.f};
  if (valid) as4 = *(const f32x4*)(aS + (size_t)s * 4);

  f32x4 e, eself;
  #pragma unroll
  for (int hh = 0; hh < 4; ++hh) {
    e[hh] = lrelu(as4[hh] + ad4[hh]);
    eself[hh] = lrelu(asi[hh] + ad4[hh]);
  }

  f32x4 mx;
  #pragma unroll
  for (int hh = 0; hh < 4; ++hh) mx[hh] = valid ? e[hh] : -1e30f;
  #pragma unroll
  for (int o = 16; o; o >>= 1) {
    #pragma unroll
    for (int hh = 0; hh < 4; ++hh) mx[hh] = fmaxf(mx[hh], __shfl_xor(mx[hh], o, 32));
  }
  #pragma unroll
  for (int hh = 0; hh < 4; ++hh) mx[hh] = fmaxf(mx[hh], eself[hh]);

  f32x4 w, z;
  #pragma unroll
  for (int hh = 0; hh < 4; ++hh) { w[hh] = valid ? __expf(e[hh] - mx[hh]) : 0.f; z[hh] = w[hh]; }
  #pragma unroll
  for (int o = 16; o; o >>= 1) {
    #pragma unroll
    for (int hh = 0; hh < 4; ++hh) z[hh] += __shfl_xor(z[hh], o, 32);
  }
  f32x4 wsf;
  #pragma unroll
  for (int hh = 0; hh < 4; ++hh) { wsf[hh] = __expf(eself[hh] - mx[hh]); z[hh] += wsf[hh]; }

  int dtot = (deg + 3) & ~3;
  const int dmax = max(dtot, __shfl_xor(dtot, 32));
  if (l < dmax) {
    ssh[wv][hf][l] = valid ? s : ipad;
    f32x4 wst = f32x4{0.f, 0.f, 0.f, 0.f};
    if (valid) wst = w;
    *(f32x4*)wsh[wv][hf][l] = wst;
  }

  f32x4 acc = f32x4{0.f, 0.f, 0.f, 0.f};
  {
    us4 u = {0, 0, 0, 0};
    if (iok) u = *(const us4*)(hb + (size_t)i * 128 + c0);
    const float ws = wsf[hd];
    #pragma unroll
    for (int q = 0; q < 4; ++q) acc[q] = ws * bf2f(u[q]);
  }
  for (int j0 = 0; j0 < dmax; j0 += 4) {
    const int s0 = ssh[wv][hf][j0],     s1 = ssh[wv][hf][j0 + 1];
    const int s2 = ssh[wv][hf][j0 + 2], s3 = ssh[wv][hf][j0 + 3];
    const float w0 = wsh[wv][hf][j0][hd],     w1 = wsh[wv][hf][j0 + 1][hd];
    const float w2 = wsh[wv][hf][j0 + 2][hd], w3 = wsh[wv][hf][j0 + 3][hd];
    const us4 u0 = *(const us4*)(hb + (size_t)s0 * 128 + c0);
    const us4 u1 = *(const us4*)(hb + (size_t)s1 * 128 + c0);
    const us4 u2 = *(const us4*)(hb + (size_t)s2 * 128 + c0);
    const us4 u3 = *(const us4*)(hb + (size_t)s3 * 128 + c0);
    #pragma unroll
    for (int q = 0; q < 4; ++q)
      acc[q] += w0 * bf2f(u0[q]) + w1 * bf2f(u1[q]) + w2 * bf2f(u2[q]) + w3 * bf2f(u3[q]);
  }

  if (!iok) return;
  const float inv = 1.f / (z[hd] + 1e-16f);
  const f32x4 bb = *(const f32x4*)(bias + c0);
  float* op = out + (size_t)i * 128 + c0;
  f32x4 res;
  #pragma unroll
  for (int q = 0; q < 4; ++q) res[q] = acc[q] * inv + bb[q];
  if (mode == 0) { *(f32x4*)op = res; }
  else {
    f32x4 cur = *(const f32x4*)op;
    #pragma unroll
    for (int q = 0; q < 4; ++q) {
      float r = cur[q] + res[q];
      if (mode == 2) r = fmaxf(r, 0.f);
      res[q] = r;
    }
    *(f32x4*)op = res;
  }
}

// ---------------- fused 2-relation GAT conv (bf16 h): out = relu(out + c + d) ------
// R9-proven staging/gather structure; NEW (safe): both relations' input loads
// hoisted to the top (2 chains in flight) and the 2 softmax butterflies
// interleaved (register-only). Staging + gather per rel identical to R9.
__global__ __launch_bounds__(256) void k_conv2(
    const unsigned short* __restrict__ hcp, const unsigned short* __restrict__ hdp,
    const float* __restrict__ aSc, const float* __restrict__ aDc,
    const float* __restrict__ aSd, const float* __restrict__ aDd,
    const int* __restrict__ srcs_c, const int* __restrict__ cnt_c,
    const int* __restrict__ srcs_d, const int* __restrict__ cnt_d,
    const float* __restrict__ bias_c, const float* __restrict__ bias_d,
    float* __restrict__ out, int fh_shift, int n)
{
  __shared__ int   ssh[4][2][2][32];        // [wave][rel][half][slot]
  __shared__ float wsh[4][2][2][32][4];
  const int wv = threadIdx.x >> 6;
  const int lane = threadIdx.x & 63;
  const int hf = lane >> 5;
  const int l  = lane & 31;
  const int i = blockIdx.x * 8 + wv * 2 + hf;
  const bool iok = i < n;
  const int ipad = iok ? i : 0;
  const int c0 = l * 4;
  const int hd = c0 >> fh_shift;

  const unsigned short* hA[2] = {hcp, hdp};
  const float* aSA[2]  = {aSc, aSd};
  const float* aDA[2]  = {aDc, aDd};
  const int*   spA[2]  = {srcs_c, srcs_d};
  const int*   cntA[2] = {cnt_c, cnt_d};

  // ---- hoisted loads: both relations' chains issued together ----
  int deg[2]; bool valid[2]; int s[2];
  f32x4 ad4[2], asi[2], as4[2];
  #pragma unroll
  for (int r = 0; r < 2; ++r) {
    deg[r] = 0;
    if (iok) { int d = cntA[r][i]; deg[r] = d > MAXDEG ? MAXDEG : d; }
  }
  #pragma unroll
  for (int r = 0; r < 2; ++r) {
    const int* sp = spA[r] + (size_t)ipad * MAXDEG;
    valid[r] = l < deg[r];
    s[r] = valid[r] ? sp[l] : ipad;
  }
  #pragma unroll
  for (int r = 0; r < 2; ++r) {
    ad4[r] = f32x4{0.f, 0.f, 0.f, 0.f};
    asi[r] = f32x4{0.f, 0.f, 0.f, 0.f};
    if (iok) {
      ad4[r] = *(const f32x4*)(aDA[r] + (size_t)i * 4);
      asi[r] = *(const f32x4*)(aSA[r] + (size_t)i * 4);
    }
  }
  #pragma unroll
  for (int r = 0; r < 2; ++r) {
    as4[r] = f32x4{0.f, 0.f, 0.f, 0.f};
    if (valid[r]) as4[r] = *(const f32x4*)(aSA[r] + (size_t)s[r] * 4);
  }

  // ---- interleaved softmax (register-only) ----
  f32x4 e[2], eself[2], mx[2];
  #pragma unroll
  for (int r = 0; r < 2; ++r)
    #pragma unroll
    for (int hh = 0; hh < 4; ++hh) {
      e[r][hh] = lrelu(as4[r][hh] + ad4[r][hh]);
      eself[r][hh] = lrelu(asi[r][hh] + ad4[r][hh]);
      mx[r][hh] = valid[r] ? e[r][hh] : -1e30f;
    }
  #pragma unroll
  for (int o = 16; o; o >>= 1)
    #pragma unroll
    for (int r = 0; r < 2; ++r)
      #pragma unroll
      for (int hh = 0; hh < 4; ++hh)
        mx[r][hh] = fmaxf(mx[r][hh], __shfl_xor(mx[r][hh], o, 32));
  f32x4 w[2], z[2];
  #pragma unroll
  for (int r = 0; r < 2; ++r)
    #pragma unroll
    for (int hh = 0; hh < 4; ++hh) {
      mx[r][hh] = fmaxf(mx[r][hh], eself[r][hh]);
      w[r][hh] = valid[r] ? __expf(e[r][hh] - mx[r][hh]) : 0.f;
      z[r][hh] = w[r][hh];
    }
  #pragma unroll
  for (int o = 16; o; o >>= 1)
    #pragma unroll
    for (int r = 0; r < 2; ++r)
      #pragma unroll
      for (int hh = 0; hh < 4; ++hh)
        z[r][hh] += __shfl_xor(z[r][hh], o, 32);
  f32x4 wsf[2], inv[2];
  #pragma unroll
  for (int r = 0; r < 2; ++r)
    #pragma unroll
    for (int hh = 0; hh < 4; ++hh) {
      wsf[r][hh] = __expf(eself[r][hh] - mx[r][hh]);
      z[r][hh] += wsf[r][hh];
      inv[r][hh] = 1.f / (z[r][hh] + 1e-16f);
    }

  // ---- per-rel stage + gather (exact R9 structure) ----
  f32x4 acc = f32x4{0.f, 0.f, 0.f, 0.f};
  #pragma unroll
  for (int rel = 0; rel < 2; ++rel) {
    int dtot = (deg[rel] + 3) & ~3;
    const int dmax = max(dtot, __shfl_xor(dtot, 32));
    if (l < dmax) {
      ssh[wv][rel][hf][l] = valid[rel] ? s[rel] : ipad;
      f32x4 wst = f32x4{0.f, 0.f, 0.f, 0.f};
      if (valid[rel]) {
        #pragma unroll
        for (int hh = 0; hh < 4; ++hh) wst[hh] = w[rel][hh] * inv[rel][hh];
      }
      *(f32x4*)wsh[wv][rel][hf][l] = wst;
    }

    const unsigned short* hmat = hA[rel];
    // self row (normalized weight)
    {
      us4 u = {0, 0, 0, 0};
      if (iok) u = *(const us4*)(hmat + (size_t)i * 128 + c0);
      const float ws = wsf[rel][hd] * inv[rel][hd];
      #pragma unroll
      for (int q = 0; q < 4; ++q) acc[q] += ws * bf2f(u[q]);
    }
    for (int j0 = 0; j0 < dmax; j0 += 4) {
      const int s0 = ssh[wv][rel][hf][j0],     s1 = ssh[wv][rel][hf][j0 + 1];
      const int s2 = ssh[wv][rel][hf][j0 + 2], s3 = ssh[wv][rel][hf][j0 + 3];
      const float w0 = wsh[wv][rel][hf][j0][hd],     w1 = wsh[wv][rel][hf][j0 + 1][hd];
      const float w2 = wsh[wv][rel][hf][j0 + 2][hd], w3 = wsh[wv][rel][hf][j0 + 3][hd];
      const us4 u0 = *(const us4*)(hmat + (size_t)s0 * 128 + c0);
      const us4 u1 = *(const us4*)(hmat + (size_t)s1 * 128 + c0);
      const us4 u2 = *(const us4*)(hmat + (size_t)s2 * 128 + c0);
      const us4 u3 = *(const us4*)(hmat + (size_t)s3 * 128 + c0);
      #pragma unroll
      for (int q = 0; q < 4; ++q)
        acc[q] += w0 * bf2f(u0[q]) + w1 * bf2f(u1[q]) + w2 * bf2f(u2[q]) + w3 * bf2f(u3[q]);
    }
  }

  if (!iok) return;
  const f32x4 bbc = *(const f32x4*)(bias_c + c0);
  const f32x4 bbd = *(const f32x4*)(bias_d + c0);
  float* op = out + (size_t)i * 128 + c0;
  const f32x4 cur = *(const f32x4*)op;
  f32x4 res;
  #pragma unroll
  for (int q = 0; q < 4; ++q)
    res[q] = fmaxf(cur[q] + acc[q] + bbc[q] + bbd[q], 0.f);
  *(f32x4*)op = res;
}

// ---------------- output heads ----------------
__global__ __launch_bounds__(256) void k_head(
    const float* __restrict__ h2, const float* __restrict__ Wy, const float* __restrict__ by,
    const float* __restrict__ Wa, const float* __restrict__ ba,
    float* __restrict__ out, int n)
{
  const int r = blockIdx.x * 4 + (threadIdx.x >> 6);
  const int L = threadIdx.x & 63;
  if (r >= n) return;
  const float a = h2[(size_t)r * 128 + L];
  const float b = h2[(size_t)r * 128 + 64 + L];
  float py = a * Wy[L] + b * Wy[64 + L];
  float pa = a * Wa[L] + b * Wa[64 + L];
  #pragma unroll
  for (int o = 32; o; o >>= 1) { py += __shfl_down(py, o); pa += __shfl_down(pa, o); }
  if (L == 0) {
    out[(size_t)r * 2]     = py + by[0];
    out[(size_t)r * 2 + 1] = pa + ba[0];
  }
}

extern "C" void kernel_launch(void* const* d_in, const int* in_sizes, int n_in,
                              void* d_out, int out_size, void* d_ws, size_t ws_size,
                              hipStream_t stream) {
  const int N = in_sizes[0] / 128;
  const int E = in_sizes[2] / 2;
  const int npad = (N + 127) & ~127;

  const float* x       = (const float*)d_in[0];
  const float* pos     = (const float*)d_in[1];
  const int*   ei_chem = (const int*)d_in[2];
  const int*   ei_cond = (const int*)d_in[3];
  const int*   ei_mol  = (const int*)d_in[4];
  const float* bp = (const float*)d_in[6];
  const float* Wy = (const float*)d_in[35];
  const float* by = (const float*)d_in[36];
  const float* Wa = (const float*)d_in[37];
  const float* ba = (const float*)d_in[38];

  char* ws = (char*)d_ws;
  size_t off = 0;
  auto alloc = [&](size_t bytes) -> void* {
    void* p = ws + off; off += (bytes + 255) & ~(size_t)255; return p;
  };
  const size_t HB = (size_t)npad * 128 * sizeof(float);
  const size_t HBH = (size_t)npad * 128 * sizeof(unsigned short);
  float* H0  = (float*)alloc(HB);
  float* ACC = (float*)alloc(HB);
  unsigned short* HRb  = (unsigned short*)alloc(HBH);
  unsigned short* HRb2 = (unsigned short*)alloc(HBH);
  int* SRC[3];
  for (int r = 0; r < 3; ++r) SRC[r] = (int*)alloc((size_t)N * MAXDEG * sizeof(int));
  int*   CUR  = (int*)alloc((size_t)3 * N * sizeof(int));
  float* GSUM = (float*)alloc(256);
  float* AS   = (float*)alloc((size_t)npad * 4 * sizeof(float));
  float* AD   = (float*)alloc((size_t)npad * 4 * sizeof(float));
  float* ASd  = (float*)alloc((size_t)npad * 4 * sizeof(float));
  float* ADd  = (float*)alloc((size_t)npad * 4 * sizeof(float));

  // prepped weight images
  PrepArgs pa{};
  const int widx[9] = {5, 7, 11, 15, 19, 21, 25, 29, 33};
  const int fhs[9]  = {0, 64, 64, 32, 0, 64, 64, 32, 0};
  unsigned short *WHI[9], *WLO[9];
  float* CSUM[9];
  for (int s = 0; s < 9; ++s) {
    WHI[s]  = (unsigned short*)alloc(NFRAG * sizeof(unsigned short));
    WLO[s]  = (unsigned short*)alloc(NFRAG * sizeof(unsigned short));
    CSUM[s] = (float*)alloc(144 * sizeof(float));
    pa.W[s] = (const float*)d_in[widx[s]];
    pa.fh[s] = fhs[s];
    pa.as_[s] = fhs[s] ? (const float*)d_in[widx[s] + 1] : nullptr;
    pa.ad_[s] = fhs[s] ? (const float*)d_in[widx[s] + 2] : nullptr;
    pa.hi[s] = WHI[s]; pa.lo[s] = WLO[s]; pa.csum[s] = CSUM[s];
  }

  hipMemsetAsync(CUR, 0, (size_t)3 * N * sizeof(int), stream);
  hipMemsetAsync(GSUM, 0, sizeof(float), stream);

  {
    const int nthreads = (3 * E + 3) / 4;
    const int sgrid = (nthreads + 255) / 256;
    k_scatter3<<<sgrid, 256, 0, stream>>>(ei_chem, ei_cond, ei_mol,
                                          CUR, SRC[0], SRC[1], SRC[2],
                                          pos, GSUM, E, N);
  }
  k_prep<<<9, 256, 0, stream>>>(pa);

  const int GG = 512;
  const float gscale = 0.1f / (float)E;
  const int cgrid = (N + 7) / 8;

  // h0 = x @ Wp + bp
  k_gmm<<<GG, 256, 0, stream>>>(x, WHI[0], WLO[0], CSUM[0], bp, H0,
                                nullptr, nullptr, nullptr, 0.f, N, npad, GF_BIAS);

  auto layer = [&](const float* Hin, float* Acc, int base, int s0) {
    const float* bc = (const float*)d_in[base + 3];
    const float* bd = (const float*)d_in[base + 7];
    const float* bm = (const float*)d_in[base + 11];
    const float* bl = (const float*)d_in[base + 13];
    // EQGAT (mol, heads=4): GEMM(bf16 out) + alpha + cshift; conv writes Acc; Wl in-place
    k_gmm<<<GG, 256, 0, stream>>>(Hin, WHI[s0+2], WLO[s0+2], CSUM[s0+2], nullptr,
                                  (float*)HRb, AS, AD, GSUM, gscale, N, npad,
                                  GF_CSHIFT | GF_ALPHA | GF_BF16);
    k_conv<<<cgrid, 256, 0, stream>>>(HRb, AS, AD, SRC[2], CUR + 2*N, bm, Acc, 5, 0, N);
    k_gmm<<<GG, 256, 0, stream>>>(Acc, WHI[s0+3], WLO[s0+3], CSUM[s0+3], bl, Acc,
                                  nullptr, nullptr, nullptr, 0.f, N, npad, GF_BIAS);
    // chem -> HRb (+AS/AD), cond -> HRb2 (+ASd/ADd), fused conv with relu
    k_gmm<<<GG, 256, 0, stream>>>(Hin, WHI[s0+0], WLO[s0+0], CSUM[s0+0], nullptr,
                                  (float*)HRb, AS, AD, nullptr, 0.f, N, npad,
                                  GF_ALPHA | GF_BF16);
    k_gmm<<<GG, 256, 0, stream>>>(Hin, WHI[s0+1], WLO[s0+1], CSUM[s0+1], nullptr,
                                  (float*)HRb2, ASd, ADd, nullptr, 0.f, N, npad,
                                  GF_ALPHA | GF_BF16);
    k_conv2<<<cgrid, 256, 0, stream>>>(HRb, HRb2, AS, AD, ASd, ADd,
                                       SRC[0], CUR + 0*N, SRC[1], CUR + 1*N,
                                       bc, bd, Acc, 6, N);
  };

  layer(H0, ACC, 7, 1);    // h1 in ACC
  layer(ACC, H0, 21, 5);   // h2 in H0

  k_head<<<(N + 3) / 4, 256, 0, stream>>>(H0, Wy, by, Wa, ba, (float*)d_out, N);
}

// Round 12
// 670.364 us; speedup vs baseline: 1.1503x; 1.1503x over previous
//
#include <hip/hip_runtime.h>
#include <math.h>

typedef short short8 __attribute__((ext_vector_type(8)));
typedef float f32x4 __attribute__((ext_vector_type(4)));
typedef unsigned short us4 __attribute__((ext_vector_type(4)));

#define MAXDEG 32
#define GF_BIAS   1
#define GF_CSHIFT 2
#define GF_ALPHA  4
#define NFRAG 18432   // 9 nt-tiles * 4 kt * 64 lanes * 8 bf16

__device__ __forceinline__ unsigned short f2bf(float f) {  // RNE f32->bf16
  unsigned u = __float_as_uint(f);
  u += 0x7FFF + ((u >> 16) & 1);
  return (unsigned short)(u >> 16);
}
__device__ __forceinline__ float bf2f(unsigned short s) { return __uint_as_float(((unsigned)s) << 16); }
__device__ __forceinline__ float lrelu(float v) { return v > 0.f ? v : 0.2f * v; }

// ---------------- CSR slot-scatter (3 relations) + fused geo reduce, 4-way ILP ------
__global__ __launch_bounds__(256) void k_scatter3(
    const int* __restrict__ ei0, const int* __restrict__ ei1, const int* __restrict__ ei2,
    int* __restrict__ cur,
    int* __restrict__ s0, int* __restrict__ s1, int* __restrict__ s2,
    const float* __restrict__ pos, float* __restrict__ gsum, int E, int N) {
  __shared__ float part[4];
  const int T4 = gridDim.x * 256;
  const int t = blockIdx.x * 256 + threadIdx.x;
  float d = 0.f;
  #pragma unroll
  for (int k = 0; k < 4; ++k) {
    const int idx = t + k * T4;
    if (idx >= 3 * E) continue;
    int rel, e;
    if (idx < E)          { rel = 0; e = idx; }
    else if (idx < 2 * E) { rel = 1; e = idx - E; }
    else                  { rel = 2; e = idx - 2 * E; }
    const int* ei = (rel == 0) ? ei0 : (rel == 1) ? ei1 : ei2;
    int* srcs     = (rel == 0) ? s0  : (rel == 1) ? s1  : s2;
    const int r = ei[e];
    const int c = ei[E + e];
    const int slot = atomicAdd(&cur[rel * N + c], 1);
    if (slot < MAXDEG) srcs[(size_t)c * MAXDEG + slot] = r;
    if (rel == 2) {
      const float dx = pos[3*r]   - pos[3*c];
      const float dy = pos[3*r+1] - pos[3*c+1];
      const float dz = pos[3*r+2] - pos[3*c+2];
      d += sqrtf(dx*dx + dy*dy + dz*dz);
    }
  }
  #pragma unroll
  for (int o = 32; o; o >>= 1) d += __shfl_down(d, o);
  if ((threadIdx.x & 63) == 0) part[threadIdx.x >> 6] = d;
  __syncthreads();
  if (threadIdx.x == 0) {
    const float s = part[0] + part[1] + part[2] + part[3];
    if (s != 0.f) atomicAdd(gsum, s);
  }
}

// ---------------- weight prep: bf16 hi/lo fragment images + alpha cols + colsums ----
struct PrepArgs {
  const float* W[9];
  const float* as_[9];
  const float* ad_[9];
  unsigned short* hi[9];
  unsigned short* lo[9];
  float* csum[9];
  int fh[9];   // 0 = no alpha cols
};

__global__ __launch_bounds__(256) void k_prep(PrepArgs p) {
  const int s = blockIdx.x;
  const int t = threadIdx.x;
  const float* W = p.W[s];
  const int fh = p.fh[s];
  __shared__ float Ws[128 * 129];
  __shared__ float alpha[128 * 8];
  {
    const f32x4* src = (const f32x4*)W;
    for (int i = t; i < 4096; i += 256) {     // 16384 floats, coalesced
      const f32x4 v = src[i];
      const int row = i >> 5;
      const int col = (i & 31) * 4;
      float* dst = &Ws[row * 129 + col];
      dst[0] = v[0]; dst[1] = v[1]; dst[2] = v[2]; dst[3] = v[3];
    }
  }
  __syncthreads();
  if (t < 128) {
    #pragma unroll
    for (int a = 0; a < 8; ++a) alpha[t * 8 + a] = 0.f;
    if (fh) {
      const int nh = 128 / fh;
      for (int h = 0; h < nh; ++h) {
        float s1 = 0.f, s2 = 0.f;
        for (int c = 0; c < fh; ++c) {
          const float w = Ws[t * 129 + h * fh + c];
          s1 += w * p.as_[s][h * fh + c];
          s2 += w * p.ad_[s][h * fh + c];
        }
        alpha[t * 8 + h] = s1;
        alpha[t * 8 + 4 + h] = s2;
      }
    }
  }
  __syncthreads();
  for (int idx = t; idx < NFRAG; idx += 256) {
    const int j = idx & 7, lane = (idx >> 3) & 63, kt = (idx >> 9) & 3, nt = idx >> 11;
    const int k = kt * 32 + (lane >> 4) * 8 + j;
    const int col = nt * 16 + (lane & 15);
    float w;
    if (col < 128) w = Ws[k * 129 + col];
    else if (col < 136) w = alpha[k * 8 + (col - 128)];
    else w = 0.f;
    const unsigned short h = f2bf(w);
    p.hi[s][idx] = h;
    p.lo[s][idx] = f2bf(w - bf2f(h));
  }
  if (t < 136) {
    float cs = 0.f;
    if (t < 128) for (int k = 0; k < 128; ++k) cs += Ws[k * 129 + t];
    else         for (int k = 0; k < 128; ++k) cs += alpha[k * 8 + (t - 128)];
    p.csum[s][t] = cs;
  }
}

// ---------------- split-bf16 MFMA GEMM, fp32 A (GEMM0 only): C bf16 ---------------
__global__ __launch_bounds__(256, 2) void k_gmm(
    const float* __restrict__ A, const unsigned short* __restrict__ Whi,
    const unsigned short* __restrict__ Wlo, const float* __restrict__ csum,
    const float* __restrict__ bias, unsigned short* __restrict__ C,
    float* __restrict__ aS, float* __restrict__ aD,
    const float* __restrict__ gsum, float gscale,
    int n, int npad, int flags)
{
  __shared__ unsigned short shi[NFRAG];
  __shared__ unsigned short slo[NFRAG];
  {
    const f32x4* srch = (const f32x4*)Whi;
    const f32x4* srcl = (const f32x4*)Wlo;
    f32x4* dsth = (f32x4*)shi;
    f32x4* dstl = (f32x4*)slo;
    for (int i = threadIdx.x; i < NFRAG / 8; i += 256) { dsth[i] = srch[i]; dstl[i] = srcl[i]; }
  }
  __syncthreads();

  const int wave = threadIdx.x >> 6, lane = threadIdx.x & 63;
  const int m = lane & 15, kq = lane >> 4;
  const float cb = (flags & GF_CSHIFT) ? gscale * gsum[0] : 0.f;

  for (int rb = blockIdx.x * 128; rb < npad; rb += gridDim.x * 128) {
    const int rw = rb + wave * 32;
    short8 ah[2][4], al[2][4];
    #pragma unroll
    for (int sub = 0; sub < 2; ++sub) {
      const int row = rw + sub * 16 + m;
      const bool ok = row < n;
      const float* ap = A + (size_t)row * 128 + kq * 8;
      #pragma unroll
      for (int kt = 0; kt < 4; ++kt) {
        f32x4 x0 = {0.f, 0.f, 0.f, 0.f}, x1 = {0.f, 0.f, 0.f, 0.f};
        if (ok) { x0 = *(const f32x4*)(ap + kt * 32); x1 = *(const f32x4*)(ap + kt * 32 + 4); }
        #pragma unroll
        for (int j = 0; j < 4; ++j) {
          unsigned short h0 = f2bf(x0[j]);
          ah[sub][kt][j] = (short)h0;
          al[sub][kt][j] = (short)f2bf(x0[j] - bf2f(h0));
          unsigned short h1 = f2bf(x1[j]);
          ah[sub][kt][4 + j] = (short)h1;
          al[sub][kt][4 + j] = (short)f2bf(x1[j] - bf2f(h1));
        }
      }
    }
    f32x4 acc[2][9];
    #pragma unroll
    for (int sub = 0; sub < 2; ++sub)
      #pragma unroll
      for (int nt = 0; nt < 9; ++nt) acc[sub][nt] = f32x4{0.f, 0.f, 0.f, 0.f};

    #pragma unroll
    for (int nt = 0; nt < 9; ++nt) {
      #pragma unroll
      for (int kt = 0; kt < 4; ++kt) {
        const int fo = ((nt * 4 + kt) * 64 + lane) * 8;
        const short8 bh = *(const short8*)&shi[fo];
        const short8 bl = *(const short8*)&slo[fo];
        #pragma unroll
        for (int sub = 0; sub < 2; ++sub) {
          acc[sub][nt] = __builtin_amdgcn_mfma_f32_16x16x32_bf16(ah[sub][kt], bh, acc[sub][nt], 0, 0, 0);
          acc[sub][nt] = __builtin_amdgcn_mfma_f32_16x16x32_bf16(al[sub][kt], bh, acc[sub][nt], 0, 0, 0);
          acc[sub][nt] = __builtin_amdgcn_mfma_f32_16x16x32_bf16(ah[sub][kt], bl, acc[sub][nt], 0, 0, 0);
        }
      }
    }
    #pragma unroll
    for (int sub = 0; sub < 2; ++sub) {
      const int rbase = rw + sub * 16 + kq * 4;
      #pragma unroll
      for (int nt = 0; nt < 8; ++nt) {
        const int col = nt * 16 + m;
        const float cs = (flags & GF_CSHIFT) ? cb * csum[col] : 0.f;
        const float bb = (flags & GF_BIAS) ? bias[col] : 0.f;
        #pragma unroll
        for (int r = 0; r < 4; ++r)
          C[(size_t)(rbase + r) * 128 + col] = f2bf(acc[sub][nt][r] + cs + bb);
      }
      if ((flags & GF_ALPHA) && m < 8) {
        const float cs = (flags & GF_CSHIFT) ? cb * csum[128 + m] : 0.f;
        #pragma unroll
        for (int r = 0; r < 4; ++r) {
          const float v = acc[sub][8][r] + cs;
          const int row = rbase + r;
          if (m < 4) aS[(size_t)row * 4 + m] = v;
          else       aD[(size_t)row * 4 + (m - 4)] = v;
        }
      }
    }
  }
}

// ---------------- bf16-A MFMA GEMM: A loads straight as short8, 2 MFMAs/fragment ---
// A storage is already bf16 -> no conversion VALU, no A-lo term (info gone at store).
// Weight side keeps hi+lo (full precision). C written bf16.
__global__ __launch_bounds__(256, 2) void k_gmmb(
    const unsigned short* __restrict__ A, const unsigned short* __restrict__ Whi,
    const unsigned short* __restrict__ Wlo, const float* __restrict__ csum,
    const float* __restrict__ bias, unsigned short* __restrict__ C,
    float* __restrict__ aS, float* __restrict__ aD,
    const float* __restrict__ gsum, float gscale,
    int n, int npad, int flags)
{
  __shared__ unsigned short shi[NFRAG];
  __shared__ unsigned short slo[NFRAG];
  {
    const f32x4* srch = (const f32x4*)Whi;
    const f32x4* srcl = (const f32x4*)Wlo;
    f32x4* dsth = (f32x4*)shi;
    f32x4* dstl = (f32x4*)slo;
    for (int i = threadIdx.x; i < NFRAG / 8; i += 256) { dsth[i] = srch[i]; dstl[i] = srcl[i]; }
  }
  __syncthreads();

  const int wave = threadIdx.x >> 6, lane = threadIdx.x & 63;
  const int m = lane & 15, kq = lane >> 4;
  const float cb = (flags & GF_CSHIFT) ? gscale * gsum[0] : 0.f;

  for (int rb = blockIdx.x * 128; rb < npad; rb += gridDim.x * 128) {
    const int rw = rb + wave * 32;
    short8 ah[2][4];
    #pragma unroll
    for (int sub = 0; sub < 2; ++sub) {
      const int row = rw + sub * 16 + m;
      const bool ok = row < n;
      const unsigned short* ap = A + (size_t)row * 128 + kq * 8;
      #pragma unroll
      for (int kt = 0; kt < 4; ++kt) {
        if (ok) ah[sub][kt] = *(const short8*)(ap + kt * 32);
        else    ah[sub][kt] = short8{0, 0, 0, 0, 0, 0, 0, 0};
      }
    }
    f32x4 acc[2][9];
    #pragma unroll
    for (int sub = 0; sub < 2; ++sub)
      #pragma unroll
      for (int nt = 0; nt < 9; ++nt) acc[sub][nt] = f32x4{0.f, 0.f, 0.f, 0.f};

    #pragma unroll
    for (int nt = 0; nt < 9; ++nt) {
      #pragma unroll
      for (int kt = 0; kt < 4; ++kt) {
        const int fo = ((nt * 4 + kt) * 64 + lane) * 8;
        const short8 bh = *(const short8*)&shi[fo];
        const short8 bl = *(const short8*)&slo[fo];
        #pragma unroll
        for (int sub = 0; sub < 2; ++sub) {
          acc[sub][nt] = __builtin_amdgcn_mfma_f32_16x16x32_bf16(ah[sub][kt], bh, acc[sub][nt], 0, 0, 0);
          acc[sub][nt] = __builtin_amdgcn_mfma_f32_16x16x32_bf16(ah[sub][kt], bl, acc[sub][nt], 0, 0, 0);
        }
      }
    }
    #pragma unroll
    for (int sub = 0; sub < 2; ++sub) {
      const int rbase = rw + sub * 16 + kq * 4;
      #pragma unroll
      for (int nt = 0; nt < 8; ++nt) {
        const int col = nt * 16 + m;
        const float cs = (flags & GF_CSHIFT) ? cb * csum[col] : 0.f;
        const float bb = (flags & GF_BIAS) ? bias[col] : 0.f;
        #pragma unroll
        for (int r = 0; r < 4; ++r)
          C[(size_t)(rbase + r) * 128 + col] = f2bf(acc[sub][nt][r] + cs + bb);
      }
      if ((flags & GF_ALPHA) && m < 8) {
        const float cs = (flags & GF_CSHIFT) ? cb * csum[128 + m] : 0.f;
        #pragma unroll
        for (int r = 0; r < 4; ++r) {
          const float v = acc[sub][8][r] + cs;
          const int row = rbase + r;
          if (m < 4) aS[(size_t)row * 4 + m] = v;
          else       aD[(size_t)row * 4 + (m - 4)] = v;
        }
      }
    }
  }
}

// ---------------- GAT conv (bf16 h rows -> bf16 out): mol relation ----------------
__global__ __launch_bounds__(256) void k_conv(
    const unsigned short* __restrict__ hb, const float* __restrict__ aS,
    const float* __restrict__ aD,
    const int* __restrict__ srcs, const int* __restrict__ cnt,
    const float* __restrict__ bias, unsigned short* __restrict__ out,
    int fh_shift, int n)
{
  __shared__ int   ssh[4][2][32];
  __shared__ float wsh[4][2][32][4];
  const int wv = threadIdx.x >> 6;
  const int lane = threadIdx.x & 63;
  const int hf = lane >> 5;
  const int l  = lane & 31;
  const int i = blockIdx.x * 8 + wv * 2 + hf;
  const bool iok = i < n;
  const int ipad = iok ? i : 0;
  const int c0 = l * 4;
  const int hd = c0 >> fh_shift;

  int deg = 0;
  if (iok) { deg = cnt[i]; if (deg > MAXDEG) deg = MAXDEG; }
  const int* sp = srcs + (size_t)ipad * MAXDEG;

  const bool valid = l < deg;
  int s = ipad;
  if (valid) s = sp[l];

  f32x4 ad4 = f32x4{0.f, 0.f, 0.f, 0.f}, asi = f32x4{0.f, 0.f, 0.f, 0.f};
  if (iok) {
    ad4 = *(const f32x4*)(aD + (size_t)i * 4);
    asi = *(const f32x4*)(aS + (size_t)i * 4);
  }
  f32x4 as4 = f32x4{0.f, 0.f, 0.f, 0.f};
  if (valid) as4 = *(const f32x4*)(aS + (size_t)s * 4);

  f32x4 e, eself;
  #pragma unroll
  for (int hh = 0; hh < 4; ++hh) {
    e[hh] = lrelu(as4[hh] + ad4[hh]);
    eself[hh] = lrelu(asi[hh] + ad4[hh]);
  }

  f32x4 mx;
  #pragma unroll
  for (int hh = 0; hh < 4; ++hh) mx[hh] = valid ? e[hh] : -1e30f;
  #pragma unroll
  for (int o = 16; o; o >>= 1) {
    #pragma unroll
    for (int hh = 0; hh < 4; ++hh) mx[hh] = fmaxf(mx[hh], __shfl_xor(mx[hh], o, 32));
  }
  #pragma unroll
  for (int hh = 0; hh < 4; ++hh) mx[hh] = fmaxf(mx[hh], eself[hh]);

  f32x4 w, z;
  #pragma unroll
  for (int hh = 0; hh < 4; ++hh) { w[hh] = valid ? __expf(e[hh] - mx[hh]) : 0.f; z[hh] = w[hh]; }
  #pragma unroll
  for (int o = 16; o; o >>= 1) {
    #pragma unroll
    for (int hh = 0; hh < 4; ++hh) z[hh] += __shfl_xor(z[hh], o, 32);
  }
  f32x4 wsf;
  #pragma unroll
  for (int hh = 0; hh < 4; ++hh) { wsf[hh] = __expf(eself[hh] - mx[hh]); z[hh] += wsf[hh]; }

  int dtot = (deg + 3) & ~3;
  const int dmax = max(dtot, __shfl_xor(dtot, 32));
  if (l < dmax) {
    ssh[wv][hf][l] = valid ? s : ipad;
    f32x4 wst = f32x4{0.f, 0.f, 0.f, 0.f};
    if (valid) wst = w;
    *(f32x4*)wsh[wv][hf][l] = wst;
  }

  f32x4 acc = f32x4{0.f, 0.f, 0.f, 0.f};
  {
    us4 u = {0, 0, 0, 0};
    if (iok) u = *(const us4*)(hb + (size_t)i * 128 + c0);
    const float ws = wsf[hd];
    #pragma unroll
    for (int q = 0; q < 4; ++q) acc[q] = ws * bf2f(u[q]);
  }
  for (int j0 = 0; j0 < dmax; j0 += 4) {
    const int s0 = ssh[wv][hf][j0],     s1 = ssh[wv][hf][j0 + 1];
    const int s2 = ssh[wv][hf][j0 + 2], s3 = ssh[wv][hf][j0 + 3];
    const float w0 = wsh[wv][hf][j0][hd],     w1 = wsh[wv][hf][j0 + 1][hd];
    const float w2 = wsh[wv][hf][j0 + 2][hd], w3 = wsh[wv][hf][j0 + 3][hd];
    const us4 u0 = *(const us4*)(hb + (size_t)s0 * 128 + c0);
    const us4 u1 = *(const us4*)(hb + (size_t)s1 * 128 + c0);
    const us4 u2 = *(const us4*)(hb + (size_t)s2 * 128 + c0);
    const us4 u3 = *(const us4*)(hb + (size_t)s3 * 128 + c0);
    #pragma unroll
    for (int q = 0; q < 4; ++q)
      acc[q] += w0 * bf2f(u0[q]) + w1 * bf2f(u1[q]) + w2 * bf2f(u2[q]) + w3 * bf2f(u3[q]);
  }

  if (!iok) return;
  const float inv = 1.f / (z[hd] + 1e-16f);
  const f32x4 bb = *(const f32x4*)(bias + c0);
  unsigned short* op = out + (size_t)i * 128 + c0;
  us4 res;
  #pragma unroll
  for (int q = 0; q < 4; ++q) res[q] = f2bf(acc[q] * inv + bb[q]);
  *(us4*)op = res;
}

// ---------------- fused 2-relation GAT conv (bf16): out = relu(out + c + d) -------
__global__ __launch_bounds__(256) void k_conv2(
    const unsigned short* __restrict__ hcp, const unsigned short* __restrict__ hdp,
    const float* __restrict__ aSc, const float* __restrict__ aDc,
    const float* __restrict__ aSd, const float* __restrict__ aDd,
    const int* __restrict__ srcs_c, const int* __restrict__ cnt_c,
    const int* __restrict__ srcs_d, const int* __restrict__ cnt_d,
    const float* __restrict__ bias_c, const float* __restrict__ bias_d,
    unsigned short* __restrict__ out, int fh_shift, int n)
{
  __shared__ int   ssh[4][2][2][32];        // [wave][rel][half][slot]
  __shared__ float wsh[4][2][2][32][4];
  const int wv = threadIdx.x >> 6;
  const int lane = threadIdx.x & 63;
  const int hf = lane >> 5;
  const int l  = lane & 31;
  const int i = blockIdx.x * 8 + wv * 2 + hf;
  const bool iok = i < n;
  const int ipad = iok ? i : 0;
  const int c0 = l * 4;
  const int hd = c0 >> fh_shift;

  const unsigned short* hA[2] = {hcp, hdp};
  const float* aSA[2]  = {aSc, aSd};
  const float* aDA[2]  = {aDc, aDd};
  const int*   spA[2]  = {srcs_c, srcs_d};
  const int*   cntA[2] = {cnt_c, cnt_d};

  // ---- hoisted loads: both relations' chains issued together ----
  int deg[2]; bool valid[2]; int s[2];
  f32x4 ad4[2], asi[2], as4[2];
  #pragma unroll
  for (int r = 0; r < 2; ++r) {
    deg[r] = 0;
    if (iok) { int d = cntA[r][i]; deg[r] = d > MAXDEG ? MAXDEG : d; }
  }
  #pragma unroll
  for (int r = 0; r < 2; ++r) {
    const int* sp = spA[r] + (size_t)ipad * MAXDEG;
    valid[r] = l < deg[r];
    s[r] = valid[r] ? sp[l] : ipad;
  }
  #pragma unroll
  for (int r = 0; r < 2; ++r) {
    ad4[r] = f32x4{0.f, 0.f, 0.f, 0.f};
    asi[r] = f32x4{0.f, 0.f, 0.f, 0.f};
    if (iok) {
      ad4[r] = *(const f32x4*)(aDA[r] + (size_t)i * 4);
      asi[r] = *(const f32x4*)(aSA[r] + (size_t)i * 4);
    }
  }
  #pragma unroll
  for (int r = 0; r < 2; ++r) {
    as4[r] = f32x4{0.f, 0.f, 0.f, 0.f};
    if (valid[r]) as4[r] = *(const f32x4*)(aSA[r] + (size_t)s[r] * 4);
  }

  // ---- interleaved softmax (register-only) ----
  f32x4 e[2], eself[2], mx[2];
  #pragma unroll
  for (int r = 0; r < 2; ++r)
    #pragma unroll
    for (int hh = 0; hh < 4; ++hh) {
      e[r][hh] = lrelu(as4[r][hh] + ad4[r][hh]);
      eself[r][hh] = lrelu(asi[r][hh] + ad4[r][hh]);
      mx[r][hh] = valid[r] ? e[r][hh] : -1e30f;
    }
  #pragma unroll
  for (int o = 16; o; o >>= 1)
    #pragma unroll
    for (int r = 0; r < 2; ++r)
      #pragma unroll
      for (int hh = 0; hh < 4; ++hh)
        mx[r][hh] = fmaxf(mx[r][hh], __shfl_xor(mx[r][hh], o, 32));
  f32x4 w[2], z[2];
  #pragma unroll
  for (int r = 0; r < 2; ++r)
    #pragma unroll
    for (int hh = 0; hh < 4; ++hh) {
      mx[r][hh] = fmaxf(mx[r][hh], eself[r][hh]);
      w[r][hh] = valid[r] ? __expf(e[r][hh] - mx[r][hh]) : 0.f;
      z[r][hh] = w[r][hh];
    }
  #pragma unroll
  for (int o = 16; o; o >>= 1)
    #pragma unroll
    for (int r = 0; r < 2; ++r)
      #pragma unroll
      for (int hh = 0; hh < 4; ++hh)
        z[r][hh] += __shfl_xor(z[r][hh], o, 32);
  f32x4 wsf[2], inv[2];
  #pragma unroll
  for (int r = 0; r < 2; ++r)
    #pragma unroll
    for (int hh = 0; hh < 4; ++hh) {
      wsf[r][hh] = __expf(eself[r][hh] - mx[r][hh]);
      z[r][hh] += wsf[r][hh];
      inv[r][hh] = 1.f / (z[r][hh] + 1e-16f);
    }

  // ---- per-rel stage + gather (R9-proven structure) ----
  f32x4 acc = f32x4{0.f, 0.f, 0.f, 0.f};
  #pragma unroll
  for (int rel = 0; rel < 2; ++rel) {
    int dtot = (deg[rel] + 3) & ~3;
    const int dmax = max(dtot, __shfl_xor(dtot, 32));
    if (l < dmax) {
      ssh[wv][rel][hf][l] = valid[rel] ? s[rel] : ipad;
      f32x4 wst = f32x4{0.f, 0.f, 0.f, 0.f};
      if (valid[rel]) {
        #pragma unroll
        for (int hh = 0; hh < 4; ++hh) wst[hh] = w[rel][hh] * inv[rel][hh];
      }
      *(f32x4*)wsh[wv][rel][hf][l] = wst;
    }

    const unsigned short* hmat = hA[rel];
    // self row (normalized weight)
    {
      us4 u = {0, 0, 0, 0};
      if (iok) u = *(const us4*)(hmat + (size_t)i * 128 + c0);
      const float ws = wsf[rel][hd] * inv[rel][hd];
      #pragma unroll
      for (int q = 0; q < 4; ++q) acc[q] += ws * bf2f(u[q]);
    }
    for (int j0 = 0; j0 < dmax; j0 += 4) {
      const int s0 = ssh[wv][rel][hf][j0],     s1 = ssh[wv][rel][hf][j0 + 1];
      const int s2 = ssh[wv][rel][hf][j0 + 2], s3 = ssh[wv][rel][hf][j0 + 3];
      const float w0 = wsh[wv][rel][hf][j0][hd],     w1 = wsh[wv][rel][hf][j0 + 1][hd];
      const float w2 = wsh[wv][rel][hf][j0 + 2][hd], w3 = wsh[wv][rel][hf][j0 + 3][hd];
      const us4 u0 = *(const us4*)(hmat + (size_t)s0 * 128 + c0);
      const us4 u1 = *(const us4*)(hmat + (size_t)s1 * 128 + c0);
      const us4 u2 = *(const us4*)(hmat + (size_t)s2 * 128 + c0);
      const us4 u3 = *(const us4*)(hmat + (size_t)s3 * 128 + c0);
      #pragma unroll
      for (int q = 0; q < 4; ++q)
        acc[q] += w0 * bf2f(u0[q]) + w1 * bf2f(u1[q]) + w2 * bf2f(u2[q]) + w3 * bf2f(u3[q]);
    }
  }

  if (!iok) return;
  const f32x4 bbc = *(const f32x4*)(bias_c + c0);
  const f32x4 bbd = *(const f32x4*)(bias_d + c0);
  unsigned short* op = out + (size_t)i * 128 + c0;
  const us4 cu = *(const us4*)op;
  us4 res;
  #pragma unroll
  for (int q = 0; q < 4; ++q)
    res[q] = f2bf(fmaxf(bf2f(cu[q]) + acc[q] + bbc[q] + bbd[q], 0.f));
  *(us4*)op = res;
}

// ---------------- output heads (bf16 h2) ----------------
__global__ __launch_bounds__(256) void k_head(
    const unsigned short* __restrict__ h2, const float* __restrict__ Wy,
    const float* __restrict__ by,
    const float* __restrict__ Wa, const float* __restrict__ ba,
    float* __restrict__ out, int n)
{
  const int r = blockIdx.x * 4 + (threadIdx.x >> 6);
  const int L = threadIdx.x & 63;
  if (r >= n) return;
  const float a = bf2f(h2[(size_t)r * 128 + L]);
  const float b = bf2f(h2[(size_t)r * 128 + 64 + L]);
  float py = a * Wy[L] + b * Wy[64 + L];
  float pa = a * Wa[L] + b * Wa[64 + L];
  #pragma unroll
  for (int o = 32; o; o >>= 1) { py += __shfl_down(py, o); pa += __shfl_down(pa, o); }
  if (L == 0) {
    out[(size_t)r * 2]     = py + by[0];
    out[(size_t)r * 2 + 1] = pa + ba[0];
  }
}

extern "C" void kernel_launch(void* const* d_in, const int* in_sizes, int n_in,
                              void* d_out, int out_size, void* d_ws, size_t ws_size,
                              hipStream_t stream) {
  const int N = in_sizes[0] / 128;
  const int E = in_sizes[2] / 2;
  const int npad = (N + 127) & ~127;

  const float* x       = (const float*)d_in[0];
  const float* pos     = (const float*)d_in[1];
  const int*   ei_chem = (const int*)d_in[2];
  const int*   ei_cond = (const int*)d_in[3];
  const int*   ei_mol  = (const int*)d_in[4];
  const float* bp = (const float*)d_in[6];
  const float* Wy = (const float*)d_in[35];
  const float* by = (const float*)d_in[36];
  const float* Wa = (const float*)d_in[37];
  const float* ba = (const float*)d_in[38];

  char* ws = (char*)d_ws;
  size_t off = 0;
  auto alloc = [&](size_t bytes) -> void* {
    void* p = ws + off; off += (bytes + 255) & ~(size_t)255; return p;
  };
  const size_t HBH = (size_t)npad * 128 * sizeof(unsigned short);
  unsigned short* H0b  = (unsigned short*)alloc(HBH);
  unsigned short* ACCb = (unsigned short*)alloc(HBH);
  unsigned short* HRb  = (unsigned short*)alloc(HBH);
  unsigned short* HRb2 = (unsigned short*)alloc(HBH);
  int* SRC[3];
  for (int r = 0; r < 3; ++r) SRC[r] = (int*)alloc((size_t)N * MAXDEG * sizeof(int));
  int*   CUR  = (int*)alloc((size_t)3 * N * sizeof(int));
  float* GSUM = (float*)alloc(256);
  float* AS   = (float*)alloc((size_t)npad * 4 * sizeof(float));
  float* AD   = (float*)alloc((size_t)npad * 4 * sizeof(float));
  float* ASd  = (float*)alloc((size_t)npad * 4 * sizeof(float));
  float* ADd  = (float*)alloc((size_t)npad * 4 * sizeof(float));

  // prepped weight images
  PrepArgs pa{};
  const int widx[9] = {5, 7, 11, 15, 19, 21, 25, 29, 33};
  const int fhs[9]  = {0, 64, 64, 32, 0, 64, 64, 32, 0};
  unsigned short *WHI[9], *WLO[9];
  float* CSUM[9];
  for (int s = 0; s < 9; ++s) {
    WHI[s]  = (unsigned short*)alloc(NFRAG * sizeof(unsigned short));
    WLO[s]  = (unsigned short*)alloc(NFRAG * sizeof(unsigned short));
    CSUM[s] = (float*)alloc(144 * sizeof(float));
    pa.W[s] = (const float*)d_in[widx[s]];
    pa.fh[s] = fhs[s];
    pa.as_[s] = fhs[s] ? (const float*)d_in[widx[s] + 1] : nullptr;
    pa.ad_[s] = fhs[s] ? (const float*)d_in[widx[s] + 2] : nullptr;
    pa.hi[s] = WHI[s]; pa.lo[s] = WLO[s]; pa.csum[s] = CSUM[s];
  }

  hipMemsetAsync(CUR, 0, (size_t)3 * N * sizeof(int), stream);
  hipMemsetAsync(GSUM, 0, sizeof(float), stream);

  {
    const int nthreads = (3 * E + 3) / 4;
    const int sgrid = (nthreads + 255) / 256;
    k_scatter3<<<sgrid, 256, 0, stream>>>(ei_chem, ei_cond, ei_mol,
                                          CUR, SRC[0], SRC[1], SRC[2],
                                          pos, GSUM, E, N);
  }
  k_prep<<<9, 256, 0, stream>>>(pa);

  const int GG = 512;
  const float gscale = 0.1f / (float)E;
  const int cgrid = (N + 7) / 8;

  // h0 = x @ Wp + bp   (fp32-A split path, bf16 out)
  k_gmm<<<GG, 256, 0, stream>>>(x, WHI[0], WLO[0], CSUM[0], bp, H0b,
                                nullptr, nullptr, nullptr, 0.f, N, npad, GF_BIAS);

  auto layer = [&](const unsigned short* Hin, unsigned short* Acc, int base, int s0) {
    const float* bc = (const float*)d_in[base + 3];
    const float* bd = (const float*)d_in[base + 7];
    const float* bm = (const float*)d_in[base + 11];
    const float* bl = (const float*)d_in[base + 13];
    // EQGAT (mol, heads=4): bf16-A GEMM + alpha + cshift; conv writes Acc; Wl in-place
    k_gmmb<<<GG, 256, 0, stream>>>(Hin, WHI[s0+2], WLO[s0+2], CSUM[s0+2], nullptr,
                                   HRb, AS, AD, GSUM, gscale, N, npad,
                                   GF_CSHIFT | GF_ALPHA);
    k_conv<<<cgrid, 256, 0, stream>>>(HRb, AS, AD, SRC[2], CUR + 2*N, bm, Acc, 5, N);
    k_gmmb<<<GG, 256, 0, stream>>>(Acc, WHI[s0+3], WLO[s0+3], CSUM[s0+3], bl, Acc,
                                   nullptr, nullptr, nullptr, 0.f, N, npad, GF_BIAS);
    // chem -> HRb (+AS/AD), cond -> HRb2 (+ASd/ADd), fused conv with relu
    k_gmmb<<<GG, 256, 0, stream>>>(Hin, WHI[s0+0], WLO[s0+0], CSUM[s0+0], nullptr,
                                   HRb, AS, AD, nullptr, 0.f, N, npad, GF_ALPHA);
    k_gmmb<<<GG, 256, 0, stream>>>(Hin, WHI[s0+1], WLO[s0+1], CSUM[s0+1], nullptr,
                                   HRb2, ASd, ADd, nullptr, 0.f, N, npad, GF_ALPHA);
    k_conv2<<<cgrid, 256, 0, stream>>>(HRb, HRb2, AS, AD, ASd, ADd,
                                       SRC[0], CUR + 0*N, SRC[1], CUR + 1*N,
                                       bc, bd, Acc, 6, N);
  };

  layer(H0b, ACCb, 7, 1);    // h1 in ACCb
  layer(ACCb, H0b, 21, 5);   // h2 in H0b

  k_head<<<(N + 3) / 4, 256, 0, stream>>>(H0b, Wy, by, Wa, ba, (float*)d_out, N);
}

// Round 13
// 656.690 us; speedup vs baseline: 1.1743x; 1.0208x over previous
//
#include <hip/hip_runtime.h>
#include <math.h>

typedef short short8 __attribute__((ext_vector_type(8)));
typedef float f32x4 __attribute__((ext_vector_type(4)));
typedef unsigned short us4 __attribute__((ext_vector_type(4)));

#define MAXDEG 32
#define GF_BIAS   1
#define GF_CSHIFT 2
#define GF_ALPHA  4
#define NFRAG 18432   // 9 nt-tiles * 4 kt * 64 lanes * 8 bf16

__device__ __forceinline__ unsigned short f2bf(float f) {  // RNE f32->bf16
  unsigned u = __float_as_uint(f);
  u += 0x7FFF + ((u >> 16) & 1);
  return (unsigned short)(u >> 16);
}
__device__ __forceinline__ float bf2f(unsigned short s) { return __uint_as_float(((unsigned)s) << 16); }
__device__ __forceinline__ float lrelu(float v) { return v > 0.f ? v : 0.2f * v; }

// ---------------- CSR slot-scatter (3 relations) + fused geo reduce, 4-way ILP ------
__global__ __launch_bounds__(256) void k_scatter3(
    const int* __restrict__ ei0, const int* __restrict__ ei1, const int* __restrict__ ei2,
    int* __restrict__ cur,
    int* __restrict__ s0, int* __restrict__ s1, int* __restrict__ s2,
    const float* __restrict__ pos, float* __restrict__ gsum, int E, int N) {
  __shared__ float part[4];
  const int T4 = gridDim.x * 256;
  const int t = blockIdx.x * 256 + threadIdx.x;
  float d = 0.f;
  #pragma unroll
  for (int k = 0; k < 4; ++k) {
    const int idx = t + k * T4;
    if (idx >= 3 * E) continue;
    int rel, e;
    if (idx < E)          { rel = 0; e = idx; }
    else if (idx < 2 * E) { rel = 1; e = idx - E; }
    else                  { rel = 2; e = idx - 2 * E; }
    const int* ei = (rel == 0) ? ei0 : (rel == 1) ? ei1 : ei2;
    int* srcs     = (rel == 0) ? s0  : (rel == 1) ? s1  : s2;
    const int r = ei[e];
    const int c = ei[E + e];
    const int slot = atomicAdd(&cur[rel * N + c], 1);
    if (slot < MAXDEG) srcs[(size_t)c * MAXDEG + slot] = r;
    if (rel == 2) {
      const float dx = pos[3*r]   - pos[3*c];
      const float dy = pos[3*r+1] - pos[3*c+1];
      const float dz = pos[3*r+2] - pos[3*c+2];
      d += sqrtf(dx*dx + dy*dy + dz*dz);
    }
  }
  #pragma unroll
  for (int o = 32; o; o >>= 1) d += __shfl_down(d, o);
  if ((threadIdx.x & 63) == 0) part[threadIdx.x >> 6] = d;
  __syncthreads();
  if (threadIdx.x == 0) {
    const float s = part[0] + part[1] + part[2] + part[3];
    if (s != 0.f) atomicAdd(gsum, s);
  }
}

// ---------------- weight prep: bf16 hi/lo fragment images + alpha cols + colsums ----
struct PrepArgs {
  const float* W[9];
  const float* as_[9];
  const float* ad_[9];
  unsigned short* hi[9];
  unsigned short* lo[9];
  float* csum[9];
  int fh[9];   // 0 = no alpha cols
};

__global__ __launch_bounds__(256) void k_prep(PrepArgs p) {
  const int s = blockIdx.x;
  const int t = threadIdx.x;
  const float* W = p.W[s];
  const int fh = p.fh[s];
  __shared__ float Ws[128 * 129];
  __shared__ float alpha[128 * 8];
  {
    const f32x4* src = (const f32x4*)W;
    for (int i = t; i < 4096; i += 256) {     // 16384 floats, coalesced
      const f32x4 v = src[i];
      const int row = i >> 5;
      const int col = (i & 31) * 4;
      float* dst = &Ws[row * 129 + col];
      dst[0] = v[0]; dst[1] = v[1]; dst[2] = v[2]; dst[3] = v[3];
    }
  }
  __syncthreads();
  if (t < 128) {
    #pragma unroll
    for (int a = 0; a < 8; ++a) alpha[t * 8 + a] = 0.f;
    if (fh) {
      const int nh = 128 / fh;
      for (int h = 0; h < nh; ++h) {
        float s1 = 0.f, s2 = 0.f;
        for (int c = 0; c < fh; ++c) {
          const float w = Ws[t * 129 + h * fh + c];
          s1 += w * p.as_[s][h * fh + c];
          s2 += w * p.ad_[s][h * fh + c];
        }
        alpha[t * 8 + h] = s1;
        alpha[t * 8 + 4 + h] = s2;
      }
    }
  }
  __syncthreads();
  for (int idx = t; idx < NFRAG; idx += 256) {
    const int j = idx & 7, lane = (idx >> 3) & 63, kt = (idx >> 9) & 3, nt = idx >> 11;
    const int k = kt * 32 + (lane >> 4) * 8 + j;
    const int col = nt * 16 + (lane & 15);
    float w;
    if (col < 128) w = Ws[k * 129 + col];
    else if (col < 136) w = alpha[k * 8 + (col - 128)];
    else w = 0.f;
    const unsigned short h = f2bf(w);
    p.hi[s][idx] = h;
    p.lo[s][idx] = f2bf(w - bf2f(h));
  }
  if (t < 136) {
    float cs = 0.f;
    if (t < 128) for (int k = 0; k < 128; ++k) cs += Ws[k * 129 + t];
    else         for (int k = 0; k < 128; ++k) cs += alpha[k * 8 + (t - 128)];
    p.csum[s][t] = cs;
  }
}

// ---------------- split-bf16 MFMA GEMM, fp32 A (GEMM0 only): C bf16 ---------------
__global__ __launch_bounds__(256, 2) void k_gmm(
    const float* __restrict__ A, const unsigned short* __restrict__ Whi,
    const unsigned short* __restrict__ Wlo, const float* __restrict__ csum,
    const float* __restrict__ bias, unsigned short* __restrict__ C,
    float* __restrict__ aS, float* __restrict__ aD,
    const float* __restrict__ gsum, float gscale,
    int n, int npad, int flags)
{
  __shared__ unsigned short shi[NFRAG];
  __shared__ unsigned short slo[NFRAG];
  {
    const f32x4* srch = (const f32x4*)Whi;
    const f32x4* srcl = (const f32x4*)Wlo;
    f32x4* dsth = (f32x4*)shi;
    f32x4* dstl = (f32x4*)slo;
    for (int i = threadIdx.x; i < NFRAG / 8; i += 256) { dsth[i] = srch[i]; dstl[i] = srcl[i]; }
  }
  __syncthreads();

  const int wave = threadIdx.x >> 6, lane = threadIdx.x & 63;
  const int m = lane & 15, kq = lane >> 4;
  const float cb = (flags & GF_CSHIFT) ? gscale * gsum[0] : 0.f;

  for (int rb = blockIdx.x * 128; rb < npad; rb += gridDim.x * 128) {
    const int rw = rb + wave * 32;
    short8 ah[2][4], al[2][4];
    #pragma unroll
    for (int sub = 0; sub < 2; ++sub) {
      const int row = rw + sub * 16 + m;
      const bool ok = row < n;
      const float* ap = A + (size_t)row * 128 + kq * 8;
      #pragma unroll
      for (int kt = 0; kt < 4; ++kt) {
        f32x4 x0 = {0.f, 0.f, 0.f, 0.f}, x1 = {0.f, 0.f, 0.f, 0.f};
        if (ok) { x0 = *(const f32x4*)(ap + kt * 32); x1 = *(const f32x4*)(ap + kt * 32 + 4); }
        #pragma unroll
        for (int j = 0; j < 4; ++j) {
          unsigned short h0 = f2bf(x0[j]);
          ah[sub][kt][j] = (short)h0;
          al[sub][kt][j] = (short)f2bf(x0[j] - bf2f(h0));
          unsigned short h1 = f2bf(x1[j]);
          ah[sub][kt][4 + j] = (short)h1;
          al[sub][kt][4 + j] = (short)f2bf(x1[j] - bf2f(h1));
        }
      }
    }
    f32x4 acc[2][9];
    #pragma unroll
    for (int sub = 0; sub < 2; ++sub)
      #pragma unroll
      for (int nt = 0; nt < 9; ++nt) acc[sub][nt] = f32x4{0.f, 0.f, 0.f, 0.f};

    #pragma unroll
    for (int nt = 0; nt < 9; ++nt) {
      #pragma unroll
      for (int kt = 0; kt < 4; ++kt) {
        const int fo = ((nt * 4 + kt) * 64 + lane) * 8;
        const short8 bh = *(const short8*)&shi[fo];
        const short8 bl = *(const short8*)&slo[fo];
        #pragma unroll
        for (int sub = 0; sub < 2; ++sub) {
          acc[sub][nt] = __builtin_amdgcn_mfma_f32_16x16x32_bf16(ah[sub][kt], bh, acc[sub][nt], 0, 0, 0);
          acc[sub][nt] = __builtin_amdgcn_mfma_f32_16x16x32_bf16(al[sub][kt], bh, acc[sub][nt], 0, 0, 0);
          acc[sub][nt] = __builtin_amdgcn_mfma_f32_16x16x32_bf16(ah[sub][kt], bl, acc[sub][nt], 0, 0, 0);
        }
      }
    }
    #pragma unroll
    for (int sub = 0; sub < 2; ++sub) {
      const int rbase = rw + sub * 16 + kq * 4;
      #pragma unroll
      for (int nt = 0; nt < 8; ++nt) {
        const int col = nt * 16 + m;
        const float cs = (flags & GF_CSHIFT) ? cb * csum[col] : 0.f;
        const float bb = (flags & GF_BIAS) ? bias[col] : 0.f;
        #pragma unroll
        for (int r = 0; r < 4; ++r)
          C[(size_t)(rbase + r) * 128 + col] = f2bf(acc[sub][nt][r] + cs + bb);
      }
      if ((flags & GF_ALPHA) && m < 8) {
        const float cs = (flags & GF_CSHIFT) ? cb * csum[128 + m] : 0.f;
        #pragma unroll
        for (int r = 0; r < 4; ++r) {
          const float v = acc[sub][8][r] + cs;
          const int row = rbase + r;
          if (m < 4) aS[(size_t)row * 4 + m] = v;
          else       aD[(size_t)row * 4 + (m - 4)] = v;
        }
      }
    }
  }
}

// ---------------- bf16-A MFMA GEMM: A loads straight as short8, 2 MFMAs/fragment ---
__global__ __launch_bounds__(256, 2) void k_gmmb(
    const unsigned short* __restrict__ A, const unsigned short* __restrict__ Whi,
    const unsigned short* __restrict__ Wlo, const float* __restrict__ csum,
    const float* __restrict__ bias, unsigned short* __restrict__ C,
    float* __restrict__ aS, float* __restrict__ aD,
    const float* __restrict__ gsum, float gscale,
    int n, int npad, int flags)
{
  __shared__ unsigned short shi[NFRAG];
  __shared__ unsigned short slo[NFRAG];
  {
    const f32x4* srch = (const f32x4*)Whi;
    const f32x4* srcl = (const f32x4*)Wlo;
    f32x4* dsth = (f32x4*)shi;
    f32x4* dstl = (f32x4*)slo;
    for (int i = threadIdx.x; i < NFRAG / 8; i += 256) { dsth[i] = srch[i]; dstl[i] = srcl[i]; }
  }
  __syncthreads();

  const int wave = threadIdx.x >> 6, lane = threadIdx.x & 63;
  const int m = lane & 15, kq = lane >> 4;
  const float cb = (flags & GF_CSHIFT) ? gscale * gsum[0] : 0.f;

  for (int rb = blockIdx.x * 128; rb < npad; rb += gridDim.x * 128) {
    const int rw = rb + wave * 32;
    short8 ah[2][4];
    #pragma unroll
    for (int sub = 0; sub < 2; ++sub) {
      const int row = rw + sub * 16 + m;
      const bool ok = row < n;
      const unsigned short* ap = A + (size_t)row * 128 + kq * 8;
      #pragma unroll
      for (int kt = 0; kt < 4; ++kt) {
        if (ok) ah[sub][kt] = *(const short8*)(ap + kt * 32);
        else    ah[sub][kt] = short8{0, 0, 0, 0, 0, 0, 0, 0};
      }
    }
    f32x4 acc[2][9];
    #pragma unroll
    for (int sub = 0; sub < 2; ++sub)
      #pragma unroll
      for (int nt = 0; nt < 9; ++nt) acc[sub][nt] = f32x4{0.f, 0.f, 0.f, 0.f};

    #pragma unroll
    for (int nt = 0; nt < 9; ++nt) {
      #pragma unroll
      for (int kt = 0; kt < 4; ++kt) {
        const int fo = ((nt * 4 + kt) * 64 + lane) * 8;
        const short8 bh = *(const short8*)&shi[fo];
        const short8 bl = *(const short8*)&slo[fo];
        #pragma unroll
        for (int sub = 0; sub < 2; ++sub) {
          acc[sub][nt] = __builtin_amdgcn_mfma_f32_16x16x32_bf16(ah[sub][kt], bh, acc[sub][nt], 0, 0, 0);
          acc[sub][nt] = __builtin_amdgcn_mfma_f32_16x16x32_bf16(ah[sub][kt], bl, acc[sub][nt], 0, 0, 0);
        }
      }
    }
    #pragma unroll
    for (int sub = 0; sub < 2; ++sub) {
      const int rbase = rw + sub * 16 + kq * 4;
      #pragma unroll
      for (int nt = 0; nt < 8; ++nt) {
        const int col = nt * 16 + m;
        const float cs = (flags & GF_CSHIFT) ? cb * csum[col] : 0.f;
        const float bb = (flags & GF_BIAS) ? bias[col] : 0.f;
        #pragma unroll
        for (int r = 0; r < 4; ++r)
          C[(size_t)(rbase + r) * 128 + col] = f2bf(acc[sub][nt][r] + cs + bb);
      }
      if ((flags & GF_ALPHA) && m < 8) {
        const float cs = (flags & GF_CSHIFT) ? cb * csum[128 + m] : 0.f;
        #pragma unroll
        for (int r = 0; r < 4; ++r) {
          const float v = acc[sub][8][r] + cs;
          const int row = rbase + r;
          if (m < 4) aS[(size_t)row * 4 + m] = v;
          else       aD[(size_t)row * 4 + (m - 4)] = v;
        }
      }
    }
  }
}

// ---------------- GAT conv (bf16, mol heads=4): no max-shift (softmax invariant) ---
__global__ __launch_bounds__(256) void k_conv(
    const unsigned short* __restrict__ hb, const float* __restrict__ aS,
    const float* __restrict__ aD,
    const int* __restrict__ srcs, const int* __restrict__ cnt,
    const float* __restrict__ bias, unsigned short* __restrict__ out,
    int fh_shift, int n)
{
  __shared__ int   ssh[4][2][32];
  __shared__ float wsh[4][2][32][4];
  const int wv = threadIdx.x >> 6;
  const int lane = threadIdx.x & 63;
  const int hf = lane >> 5;
  const int l  = lane & 31;
  const int i = blockIdx.x * 8 + wv * 2 + hf;
  const bool iok = i < n;
  const int ipad = iok ? i : 0;
  const int c0 = l * 4;
  const int hd = c0 >> fh_shift;

  int deg = 0;
  if (iok) { deg = cnt[i]; if (deg > MAXDEG) deg = MAXDEG; }
  const int* sp = srcs + (size_t)ipad * MAXDEG;

  const bool valid = l < deg;
  int s = ipad;
  if (valid) s = sp[l];

  f32x4 ad4 = f32x4{0.f, 0.f, 0.f, 0.f}, asi = f32x4{0.f, 0.f, 0.f, 0.f};
  if (iok) {
    ad4 = *(const f32x4*)(aD + (size_t)i * 4);
    asi = *(const f32x4*)(aS + (size_t)i * 4);
  }
  f32x4 as4 = f32x4{0.f, 0.f, 0.f, 0.f};
  if (valid) as4 = *(const f32x4*)(aS + (size_t)s * 4);

  // softmax without max-shift (values bounded; exact up to rounding)
  f32x4 w, z, wsf;
  #pragma unroll
  for (int hh = 0; hh < 4; ++hh) {
    w[hh] = valid ? __expf(lrelu(as4[hh] + ad4[hh])) : 0.f;
    z[hh] = w[hh];
  }
  #pragma unroll
  for (int o = 16; o; o >>= 1) {
    #pragma unroll
    for (int hh = 0; hh < 4; ++hh) z[hh] += __shfl_xor(z[hh], o, 32);
  }
  #pragma unroll
  for (int hh = 0; hh < 4; ++hh) {
    wsf[hh] = __expf(lrelu(asi[hh] + ad4[hh]));
    z[hh] += wsf[hh];
  }

  int dtot = (deg + 3) & ~3;
  const int dmax = max(dtot, __shfl_xor(dtot, 32));
  if (l < dmax) {
    ssh[wv][hf][l] = valid ? s : ipad;
    f32x4 wst = f32x4{0.f, 0.f, 0.f, 0.f};
    if (valid) wst = w;
    *(f32x4*)wsh[wv][hf][l] = wst;
  }

  f32x4 acc = f32x4{0.f, 0.f, 0.f, 0.f};
  {
    us4 u = {0, 0, 0, 0};
    if (iok) u = *(const us4*)(hb + (size_t)i * 128 + c0);
    const float ws = wsf[hd];
    #pragma unroll
    for (int q = 0; q < 4; ++q) acc[q] = ws * bf2f(u[q]);
  }
  for (int j0 = 0; j0 < dmax; j0 += 4) {
    const int s0 = ssh[wv][hf][j0],     s1 = ssh[wv][hf][j0 + 1];
    const int s2 = ssh[wv][hf][j0 + 2], s3 = ssh[wv][hf][j0 + 3];
    const float w0 = wsh[wv][hf][j0][hd],     w1 = wsh[wv][hf][j0 + 1][hd];
    const float w2 = wsh[wv][hf][j0 + 2][hd], w3 = wsh[wv][hf][j0 + 3][hd];
    const us4 u0 = *(const us4*)(hb + (size_t)s0 * 128 + c0);
    const us4 u1 = *(const us4*)(hb + (size_t)s1 * 128 + c0);
    const us4 u2 = *(const us4*)(hb + (size_t)s2 * 128 + c0);
    const us4 u3 = *(const us4*)(hb + (size_t)s3 * 128 + c0);
    #pragma unroll
    for (int q = 0; q < 4; ++q)
      acc[q] += w0 * bf2f(u0[q]) + w1 * bf2f(u1[q]) + w2 * bf2f(u2[q]) + w3 * bf2f(u3[q]);
  }

  if (!iok) return;
  const float inv = 1.f / (z[hd] + 1e-16f);
  const f32x4 bb = *(const f32x4*)(bias + c0);
  unsigned short* op = out + (size_t)i * 128 + c0;
  us4 res;
  #pragma unroll
  for (int q = 0; q < 4; ++q) res[q] = f2bf(acc[q] * inv + bb[q]);
  *(us4*)op = res;
}

// ---------------- fused 2-relation GAT conv (bf16, heads=2): 2-head softmax -------
// chem/cond have heads=2 -> float2 head math (was wasting half the exp+butterfly),
// no max-shift, staged weights 2-wide. Gather structure = R12-proven.
__global__ __launch_bounds__(256) void k_conv2(
    const unsigned short* __restrict__ hcp, const unsigned short* __restrict__ hdp,
    const float* __restrict__ aSc, const float* __restrict__ aDc,
    const float* __restrict__ aSd, const float* __restrict__ aDd,
    const int* __restrict__ srcs_c, const int* __restrict__ cnt_c,
    const int* __restrict__ srcs_d, const int* __restrict__ cnt_d,
    const float* __restrict__ bias_c, const float* __restrict__ bias_d,
    unsigned short* __restrict__ out, int n)
{
  __shared__ int   ssh[4][2][2][32];        // [wave][rel][half][slot]
  __shared__ float wsh[4][2][2][32][2];
  const int wv = threadIdx.x >> 6;
  const int lane = threadIdx.x & 63;
  const int hf = lane >> 5;
  const int l  = lane & 31;
  const int i = blockIdx.x * 8 + wv * 2 + hf;
  const bool iok = i < n;
  const int ipad = iok ? i : 0;
  const int c0 = l * 4;
  const int hd = c0 >> 6;                   // heads=2

  const unsigned short* hA[2] = {hcp, hdp};
  const float* aSA[2]  = {aSc, aSd};
  const float* aDA[2]  = {aDc, aDd};
  const int*   spA[2]  = {srcs_c, srcs_d};
  const int*   cntA[2] = {cnt_c, cnt_d};

  // ---- hoisted loads: both relations' chains issued together ----
  int deg[2]; bool valid[2]; int s[2];
  float2 ad2[2], asi2[2], as2[2];
  #pragma unroll
  for (int r = 0; r < 2; ++r) {
    deg[r] = 0;
    if (iok) { int d = cntA[r][i]; deg[r] = d > MAXDEG ? MAXDEG : d; }
  }
  #pragma unroll
  for (int r = 0; r < 2; ++r) {
    const int* sp = spA[r] + (size_t)ipad * MAXDEG;
    valid[r] = l < deg[r];
    s[r] = valid[r] ? sp[l] : ipad;
  }
  #pragma unroll
  for (int r = 0; r < 2; ++r) {
    ad2[r] = float2{0.f, 0.f};
    asi2[r] = float2{0.f, 0.f};
    if (iok) {
      ad2[r] = *(const float2*)(aDA[r] + (size_t)i * 4);
      asi2[r] = *(const float2*)(aSA[r] + (size_t)i * 4);
    }
  }
  #pragma unroll
  for (int r = 0; r < 2; ++r) {
    as2[r] = float2{0.f, 0.f};
    if (valid[r]) as2[r] = *(const float2*)(aSA[r] + (size_t)s[r] * 4);
  }

  // ---- interleaved 2-head softmax, no max-shift ----
  float w0_[2], w1_[2], z0_[2], z1_[2], wsf0_[2], wsf1_[2];
  #pragma unroll
  for (int r = 0; r < 2; ++r) {
    w0_[r] = valid[r] ? __expf(lrelu(as2[r].x + ad2[r].x)) : 0.f;
    w1_[r] = valid[r] ? __expf(lrelu(as2[r].y + ad2[r].y)) : 0.f;
    z0_[r] = w0_[r]; z1_[r] = w1_[r];
  }
  #pragma unroll
  for (int o = 16; o; o >>= 1)
    #pragma unroll
    for (int r = 0; r < 2; ++r) {
      z0_[r] += __shfl_xor(z0_[r], o, 32);
      z1_[r] += __shfl_xor(z1_[r], o, 32);
    }
  #pragma unroll
  for (int r = 0; r < 2; ++r) {
    wsf0_[r] = __expf(lrelu(asi2[r].x + ad2[r].x));
    wsf1_[r] = __expf(lrelu(asi2[r].y + ad2[r].y));
    z0_[r] += wsf0_[r];
    z1_[r] += wsf1_[r];
  }

  // ---- per-rel stage + gather (R12-proven structure, 2-wide weights) ----
  f32x4 acc = f32x4{0.f, 0.f, 0.f, 0.f};
  #pragma unroll
  for (int rel = 0; rel < 2; ++rel) {
    const float i0 = 1.f / (z0_[rel] + 1e-16f);
    const float i1 = 1.f / (z1_[rel] + 1e-16f);
    int dtot = (deg[rel] + 3) & ~3;
    const int dmax = max(dtot, __shfl_xor(dtot, 32));
    if (l < dmax) {
      ssh[wv][rel][hf][l] = valid[rel] ? s[rel] : ipad;
      float2 wst = float2{0.f, 0.f};
      if (valid[rel]) wst = float2{w0_[rel] * i0, w1_[rel] * i1};
      *(float2*)wsh[wv][rel][hf][l] = wst;
    }

    const unsigned short* hmat = hA[rel];
    // self row (normalized weight)
    {
      us4 u = {0, 0, 0, 0};
      if (iok) u = *(const us4*)(hmat + (size_t)i * 128 + c0);
      const float ws = (hd == 0) ? wsf0_[rel] * i0 : wsf1_[rel] * i1;
      #pragma unroll
      for (int q = 0; q < 4; ++q) acc[q] += ws * bf2f(u[q]);
    }
    for (int j0 = 0; j0 < dmax; j0 += 4) {
      const int s0 = ssh[wv][rel][hf][j0],     s1 = ssh[wv][rel][hf][j0 + 1];
      const int s2 = ssh[wv][rel][hf][j0 + 2], s3 = ssh[wv][rel][hf][j0 + 3];
      const float w0 = wsh[wv][rel][hf][j0][hd],     w1 = wsh[wv][rel][hf][j0 + 1][hd];
      const float w2 = wsh[wv][rel][hf][j0 + 2][hd], w3 = wsh[wv][rel][hf][j0 + 3][hd];
      const us4 u0 = *(const us4*)(hmat + (size_t)s0 * 128 + c0);
      const us4 u1 = *(const us4*)(hmat + (size_t)s1 * 128 + c0);
      const us4 u2 = *(const us4*)(hmat + (size_t)s2 * 128 + c0);
      const us4 u3 = *(const us4*)(hmat + (size_t)s3 * 128 + c0);
      #pragma unroll
      for (int q = 0; q < 4; ++q)
        acc[q] += w0 * bf2f(u0[q]) + w1 * bf2f(u1[q]) + w2 * bf2f(u2[q]) + w3 * bf2f(u3[q]);
    }
  }

  if (!iok) return;
  const f32x4 bbc = *(const f32x4*)(bias_c + c0);
  const f32x4 bbd = *(const f32x4*)(bias_d + c0);
  unsigned short* op = out + (size_t)i * 128 + c0;
  const us4 cu = *(const us4*)op;
  us4 res;
  #pragma unroll
  for (int q = 0; q < 4; ++q)
    res[q] = f2bf(fmaxf(bf2f(cu[q]) + acc[q] + bbc[q] + bbd[q], 0.f));
  *(us4*)op = res;
}

// ---------------- output heads (bf16 h2) ----------------
__global__ __launch_bounds__(256) void k_head(
    const unsigned short* __restrict__ h2, const float* __restrict__ Wy,
    const float* __restrict__ by,
    const float* __restrict__ Wa, const float* __restrict__ ba,
    float* __restrict__ out, int n)
{
  const int r = blockIdx.x * 4 + (threadIdx.x >> 6);
  const int L = threadIdx.x & 63;
  if (r >= n) return;
  const float a = bf2f(h2[(size_t)r * 128 + L]);
  const float b = bf2f(h2[(size_t)r * 128 + 64 + L]);
  float py = a * Wy[L] + b * Wy[64 + L];
  float pa = a * Wa[L] + b * Wa[64 + L];
  #pragma unroll
  for (int o = 32; o; o >>= 1) { py += __shfl_down(py, o); pa += __shfl_down(pa, o); }
  if (L == 0) {
    out[(size_t)r * 2]     = py + by[0];
    out[(size_t)r * 2 + 1] = pa + ba[0];
  }
}

extern "C" void kernel_launch(void* const* d_in, const int* in_sizes, int n_in,
                              void* d_out, int out_size, void* d_ws, size_t ws_size,
                              hipStream_t stream) {
  const int N = in_sizes[0] / 128;
  const int E = in_sizes[2] / 2;
  const int npad = (N + 127) & ~127;

  const float* x       = (const float*)d_in[0];
  const float* pos     = (const float*)d_in[1];
  const int*   ei_chem = (const int*)d_in[2];
  const int*   ei_cond = (const int*)d_in[3];
  const int*   ei_mol  = (const int*)d_in[4];
  const float* bp = (const float*)d_in[6];
  const float* Wy = (const float*)d_in[35];
  const float* by = (const float*)d_in[36];
  const float* Wa = (const float*)d_in[37];
  const float* ba = (const float*)d_in[38];

  char* ws = (char*)d_ws;
  size_t off = 0;
  auto alloc = [&](size_t bytes) -> void* {
    void* p = ws + off; off += (bytes + 255) & ~(size_t)255; return p;
  };
  const size_t HBH = (size_t)npad * 128 * sizeof(unsigned short);
  unsigned short* H0b  = (unsigned short*)alloc(HBH);
  unsigned short* ACCb = (unsigned short*)alloc(HBH);
  unsigned short* HRb  = (unsigned short*)alloc(HBH);
  unsigned short* HRb2 = (unsigned short*)alloc(HBH);
  int* SRC[3];
  for (int r = 0; r < 3; ++r) SRC[r] = (int*)alloc((size_t)N * MAXDEG * sizeof(int));
  int*   CUR  = (int*)alloc((size_t)3 * N * sizeof(int));
  float* GSUM = (float*)alloc(256);
  float* AS   = (float*)alloc((size_t)npad * 4 * sizeof(float));
  float* AD   = (float*)alloc((size_t)npad * 4 * sizeof(float));
  float* ASd  = (float*)alloc((size_t)npad * 4 * sizeof(float));
  float* ADd  = (float*)alloc((size_t)npad * 4 * sizeof(float));

  // prepped weight images
  PrepArgs pa{};
  const int widx[9] = {5, 7, 11, 15, 19, 21, 25, 29, 33};
  const int fhs[9]  = {0, 64, 64, 32, 0, 64, 64, 32, 0};
  unsigned short *WHI[9], *WLO[9];
  float* CSUM[9];
  for (int s = 0; s < 9; ++s) {
    WHI[s]  = (unsigned short*)alloc(NFRAG * sizeof(unsigned short));
    WLO[s]  = (unsigned short*)alloc(NFRAG * sizeof(unsigned short));
    CSUM[s] = (float*)alloc(144 * sizeof(float));
    pa.W[s] = (const float*)d_in[widx[s]];
    pa.fh[s] = fhs[s];
    pa.as_[s] = fhs[s] ? (const float*)d_in[widx[s] + 1] : nullptr;
    pa.ad_[s] = fhs[s] ? (const float*)d_in[widx[s] + 2] : nullptr;
    pa.hi[s] = WHI[s]; pa.lo[s] = WLO[s]; pa.csum[s] = CSUM[s];
  }

  hipMemsetAsync(CUR, 0, (size_t)3 * N * sizeof(int), stream);
  hipMemsetAsync(GSUM, 0, sizeof(float), stream);

  {
    const int nthreads = (3 * E + 3) / 4;
    const int sgrid = (nthreads + 255) / 256;
    k_scatter3<<<sgrid, 256, 0, stream>>>(ei_chem, ei_cond, ei_mol,
                                          CUR, SRC[0], SRC[1], SRC[2],
                                          pos, GSUM, E, N);
  }
  k_prep<<<9, 256, 0, stream>>>(pa);

  const int GG = 512;
  const float gscale = 0.1f / (float)E;
  const int cgrid = (N + 7) / 8;

  // h0 = x @ Wp + bp   (fp32-A split path, bf16 out)
  k_gmm<<<GG, 256, 0, stream>>>(x, WHI[0], WLO[0], CSUM[0], bp, H0b,
                                nullptr, nullptr, nullptr, 0.f, N, npad, GF_BIAS);

  auto layer = [&](const unsigned short* Hin, unsigned short* Acc, int base, int s0) {
    const float* bc = (const float*)d_in[base + 3];
    const float* bd = (const float*)d_in[base + 7];
    const float* bm = (const float*)d_in[base + 11];
    const float* bl = (const float*)d_in[base + 13];
    // EQGAT (mol, heads=4): bf16-A GEMM + alpha + cshift; conv writes Acc; Wl in-place
    k_gmmb<<<GG, 256, 0, stream>>>(Hin, WHI[s0+2], WLO[s0+2], CSUM[s0+2], nullptr,
                                   HRb, AS, AD, GSUM, gscale, N, npad,
                                   GF_CSHIFT | GF_ALPHA);
    k_conv<<<cgrid, 256, 0, stream>>>(HRb, AS, AD, SRC[2], CUR + 2*N, bm, Acc, 5, N);
    k_gmmb<<<GG, 256, 0, stream>>>(Acc, WHI[s0+3], WLO[s0+3], CSUM[s0+3], bl, Acc,
                                   nullptr, nullptr, nullptr, 0.f, N, npad, GF_BIAS);
    // chem -> HRb (+AS/AD), cond -> HRb2 (+ASd/ADd), fused conv with relu
    k_gmmb<<<GG, 256, 0, stream>>>(Hin, WHI[s0+0], WLO[s0+0], CSUM[s0+0], nullptr,
                                   HRb, AS, AD, nullptr, 0.f, N, npad, GF_ALPHA);
    k_gmmb<<<GG, 256, 0, stream>>>(Hin, WHI[s0+1], WLO[s0+1], CSUM[s0+1], nullptr,
                                   HRb2, ASd, ADd, nullptr, 0.f, N, npad, GF_ALPHA);
    k_conv2<<<cgrid, 256, 0, stream>>>(HRb, HRb2, AS, AD, ASd, ADd,
                                       SRC[0], CUR + 0*N, SRC[1], CUR + 1*N,
                                       bc, bd, Acc, N);
  };

  layer(H0b, ACCb, 7, 1);    // h1 in ACCb
  layer(ACCb, H0b, 21, 5);   // h2 in H0b

  k_head<<<(N + 3) / 4, 256, 0, stream>>>(H0b, Wy, by, Wa, ba, (float*)d_out, N);
}

// Round 14
// 655.079 us; speedup vs baseline: 1.1772x; 1.0025x over previous
//
#include <hip/hip_runtime.h>
#include <math.h>

typedef short short8 __attribute__((ext_vector_type(8)));
typedef float f32x4 __attribute__((ext_vector_type(4)));
typedef unsigned short us4 __attribute__((ext_vector_type(4)));

#define MAXDEG 32
#define GF_BIAS   1
#define GF_CSHIFT 2
#define GF_ALPHA  4
#define NFRAG 18432   // 9 nt-tiles * 4 kt * 64 lanes * 8 bf16

__device__ __forceinline__ unsigned short f2bf(float f) {  // RNE f32->bf16
  unsigned u = __float_as_uint(f);
  u += 0x7FFF + ((u >> 16) & 1);
  return (unsigned short)(u >> 16);
}
__device__ __forceinline__ float bf2f(unsigned short s) { return __uint_as_float(((unsigned)s) << 16); }
__device__ __forceinline__ float lrelu(float v) { return v > 0.f ? v : 0.2f * v; }

// ---------------- CSR slot-scatter (3 relations) + fused geo reduce ----------------
// 1 edge/thread (R4-proven 53us): max TLP wins for latency-bound atomic chains;
// R6's 4-way ILP with 4x fewer threads measured SLOWER (72us, Occ 32%).
__global__ __launch_bounds__(256) void k_scatter3(
    const int* __restrict__ ei0, const int* __restrict__ ei1, const int* __restrict__ ei2,
    int* __restrict__ cur,
    int* __restrict__ s0, int* __restrict__ s1, int* __restrict__ s2,
    const float* __restrict__ pos, float* __restrict__ gsum, int E, int N) {
  __shared__ float part[4];
  const int t = blockIdx.x * 256 + threadIdx.x;
  float d = 0.f;
  if (t < 3 * E) {
    int rel, e;
    if (t < E)          { rel = 0; e = t; }
    else if (t < 2 * E) { rel = 1; e = t - E; }
    else                { rel = 2; e = t - 2 * E; }
    const int* ei = (rel == 0) ? ei0 : (rel == 1) ? ei1 : ei2;
    int* srcs     = (rel == 0) ? s0  : (rel == 1) ? s1  : s2;
    const int r = ei[e];
    const int c = ei[E + e];
    const int slot = atomicAdd(&cur[rel * N + c], 1);
    if (slot < MAXDEG) srcs[(size_t)c * MAXDEG + slot] = r;
    if (rel == 2) {
      const float dx = pos[3*r]   - pos[3*c];
      const float dy = pos[3*r+1] - pos[3*c+1];
      const float dz = pos[3*r+2] - pos[3*c+2];
      d = sqrtf(dx*dx + dy*dy + dz*dz);
    }
  }
  #pragma unroll
  for (int o = 32; o; o >>= 1) d += __shfl_down(d, o);
  if ((threadIdx.x & 63) == 0) part[threadIdx.x >> 6] = d;
  __syncthreads();
  if (threadIdx.x == 0) {
    const float s = part[0] + part[1] + part[2] + part[3];
    if (s != 0.f) atomicAdd(gsum, s);
  }
}

// ---------------- weight prep: bf16 hi/lo fragment images + alpha cols + colsums ----
struct PrepArgs {
  const float* W[9];
  const float* as_[9];
  const float* ad_[9];
  unsigned short* hi[9];
  unsigned short* lo[9];
  float* csum[9];
  int fh[9];   // 0 = no alpha cols
};

__global__ __launch_bounds__(256) void k_prep(PrepArgs p) {
  const int s = blockIdx.x;
  const int t = threadIdx.x;
  const float* W = p.W[s];
  const int fh = p.fh[s];
  __shared__ float Ws[128 * 129];
  __shared__ float alpha[128 * 8];
  {
    const f32x4* src = (const f32x4*)W;
    for (int i = t; i < 4096; i += 256) {     // 16384 floats, coalesced
      const f32x4 v = src[i];
      const int row = i >> 5;
      const int col = (i & 31) * 4;
      float* dst = &Ws[row * 129 + col];
      dst[0] = v[0]; dst[1] = v[1]; dst[2] = v[2]; dst[3] = v[3];
    }
  }
  __syncthreads();
  if (t < 128) {
    #pragma unroll
    for (int a = 0; a < 8; ++a) alpha[t * 8 + a] = 0.f;
    if (fh) {
      const int nh = 128 / fh;
      for (int h = 0; h < nh; ++h) {
        float s1 = 0.f, s2 = 0.f;
        for (int c = 0; c < fh; ++c) {
          const float w = Ws[t * 129 + h * fh + c];
          s1 += w * p.as_[s][h * fh + c];
          s2 += w * p.ad_[s][h * fh + c];
        }
        alpha[t * 8 + h] = s1;
        alpha[t * 8 + 4 + h] = s2;
      }
    }
  }
  __syncthreads();
  for (int idx = t; idx < NFRAG; idx += 256) {
    const int j = idx & 7, lane = (idx >> 3) & 63, kt = (idx >> 9) & 3, nt = idx >> 11;
    const int k = kt * 32 + (lane >> 4) * 8 + j;
    const int col = nt * 16 + (lane & 15);
    float w;
    if (col < 128) w = Ws[k * 129 + col];
    else if (col < 136) w = alpha[k * 8 + (col - 128)];
    else w = 0.f;
    const unsigned short h = f2bf(w);
    p.hi[s][idx] = h;
    p.lo[s][idx] = f2bf(w - bf2f(h));
  }
  if (t < 136) {
    float cs = 0.f;
    if (t < 128) for (int k = 0; k < 128; ++k) cs += Ws[k * 129 + t];
    else         for (int k = 0; k < 128; ++k) cs += alpha[k * 8 + (t - 128)];
    p.csum[s][t] = cs;
  }
}

// ---------------- split-bf16 MFMA GEMM, fp32 A (GEMM0 only): C bf16 ---------------
__global__ __launch_bounds__(256, 2) void k_gmm(
    const float* __restrict__ A, const unsigned short* __restrict__ Whi,
    const unsigned short* __restrict__ Wlo, const float* __restrict__ csum,
    const float* __restrict__ bias, unsigned short* __restrict__ C,
    float* __restrict__ aS, float* __restrict__ aD,
    const float* __restrict__ gsum, float gscale,
    int n, int npad, int flags)
{
  __shared__ unsigned short shi[NFRAG];
  __shared__ unsigned short slo[NFRAG];
  {
    const f32x4* srch = (const f32x4*)Whi;
    const f32x4* srcl = (const f32x4*)Wlo;
    f32x4* dsth = (f32x4*)shi;
    f32x4* dstl = (f32x4*)slo;
    for (int i = threadIdx.x; i < NFRAG / 8; i += 256) { dsth[i] = srch[i]; dstl[i] = srcl[i]; }
  }
  __syncthreads();

  const int wave = threadIdx.x >> 6, lane = threadIdx.x & 63;
  const int m = lane & 15, kq = lane >> 4;
  const float cb = (flags & GF_CSHIFT) ? gscale * gsum[0] : 0.f;

  for (int rb = blockIdx.x * 128; rb < npad; rb += gridDim.x * 128) {
    const int rw = rb + wave * 32;
    short8 ah[2][4], al[2][4];
    #pragma unroll
    for (int sub = 0; sub < 2; ++sub) {
      const int row = rw + sub * 16 + m;
      const bool ok = row < n;
      const float* ap = A + (size_t)row * 128 + kq * 8;
      #pragma unroll
      for (int kt = 0; kt < 4; ++kt) {
        f32x4 x0 = {0.f, 0.f, 0.f, 0.f}, x1 = {0.f, 0.f, 0.f, 0.f};
        if (ok) { x0 = *(const f32x4*)(ap + kt * 32); x1 = *(const f32x4*)(ap + kt * 32 + 4); }
        #pragma unroll
        for (int j = 0; j < 4; ++j) {
          unsigned short h0 = f2bf(x0[j]);
          ah[sub][kt][j] = (short)h0;
          al[sub][kt][j] = (short)f2bf(x0[j] - bf2f(h0));
          unsigned short h1 = f2bf(x1[j]);
          ah[sub][kt][4 + j] = (short)h1;
          al[sub][kt][4 + j] = (short)f2bf(x1[j] - bf2f(h1));
        }
      }
    }
    f32x4 acc[2][9];
    #pragma unroll
    for (int sub = 0; sub < 2; ++sub)
      #pragma unroll
      for (int nt = 0; nt < 9; ++nt) acc[sub][nt] = f32x4{0.f, 0.f, 0.f, 0.f};

    #pragma unroll
    for (int nt = 0; nt < 9; ++nt) {
      #pragma unroll
      for (int kt = 0; kt < 4; ++kt) {
        const int fo = ((nt * 4 + kt) * 64 + lane) * 8;
        const short8 bh = *(const short8*)&shi[fo];
        const short8 bl = *(const short8*)&slo[fo];
        #pragma unroll
        for (int sub = 0; sub < 2; ++sub) {
          acc[sub][nt] = __builtin_amdgcn_mfma_f32_16x16x32_bf16(ah[sub][kt], bh, acc[sub][nt], 0, 0, 0);
          acc[sub][nt] = __builtin_amdgcn_mfma_f32_16x16x32_bf16(al[sub][kt], bh, acc[sub][nt], 0, 0, 0);
          acc[sub][nt] = __builtin_amdgcn_mfma_f32_16x16x32_bf16(ah[sub][kt], bl, acc[sub][nt], 0, 0, 0);
        }
      }
    }
    #pragma unroll
    for (int sub = 0; sub < 2; ++sub) {
      const int rbase = rw + sub * 16 + kq * 4;
      #pragma unroll
      for (int nt = 0; nt < 8; ++nt) {
        const int col = nt * 16 + m;
        const float cs = (flags & GF_CSHIFT) ? cb * csum[col] : 0.f;
        const float bb = (flags & GF_BIAS) ? bias[col] : 0.f;
        #pragma unroll
        for (int r = 0; r < 4; ++r)
          C[(size_t)(rbase + r) * 128 + col] = f2bf(acc[sub][nt][r] + cs + bb);
      }
      if ((flags & GF_ALPHA) && m < 8) {
        const float cs = (flags & GF_CSHIFT) ? cb * csum[128 + m] : 0.f;
        #pragma unroll
        for (int r = 0; r < 4; ++r) {
          const float v = acc[sub][8][r] + cs;
          const int row = rbase + r;
          if (m < 4) aS[(size_t)row * 4 + m] = v;
          else       aD[(size_t)row * 4 + (m - 4)] = v;
        }
      }
    }
  }
}

// ---------------- bf16-A MFMA GEMM: A loads straight as short8, 2 MFMAs/fragment ---
__global__ __launch_bounds__(256, 2) void k_gmmb(
    const unsigned short* __restrict__ A, const unsigned short* __restrict__ Whi,
    const unsigned short* __restrict__ Wlo, const float* __restrict__ csum,
    const float* __restrict__ bias, unsigned short* __restrict__ C,
    float* __restrict__ aS, float* __restrict__ aD,
    const float* __restrict__ gsum, float gscale,
    int n, int npad, int flags)
{
  __shared__ unsigned short shi[NFRAG];
  __shared__ unsigned short slo[NFRAG];
  {
    const f32x4* srch = (const f32x4*)Whi;
    const f32x4* srcl = (const f32x4*)Wlo;
    f32x4* dsth = (f32x4*)shi;
    f32x4* dstl = (f32x4*)slo;
    for (int i = threadIdx.x; i < NFRAG / 8; i += 256) { dsth[i] = srch[i]; dstl[i] = srcl[i]; }
  }
  __syncthreads();

  const int wave = threadIdx.x >> 6, lane = threadIdx.x & 63;
  const int m = lane & 15, kq = lane >> 4;
  const float cb = (flags & GF_CSHIFT) ? gscale * gsum[0] : 0.f;

  for (int rb = blockIdx.x * 128; rb < npad; rb += gridDim.x * 128) {
    const int rw = rb + wave * 32;
    short8 ah[2][4];
    #pragma unroll
    for (int sub = 0; sub < 2; ++sub) {
      const int row = rw + sub * 16 + m;
      const bool ok = row < n;
      const unsigned short* ap = A + (size_t)row * 128 + kq * 8;
      #pragma unroll
      for (int kt = 0; kt < 4; ++kt) {
        if (ok) ah[sub][kt] = *(const short8*)(ap + kt * 32);
        else    ah[sub][kt] = short8{0, 0, 0, 0, 0, 0, 0, 0};
      }
    }
    f32x4 acc[2][9];
    #pragma unroll
    for (int sub = 0; sub < 2; ++sub)
      #pragma unroll
      for (int nt = 0; nt < 9; ++nt) acc[sub][nt] = f32x4{0.f, 0.f, 0.f, 0.f};

    #pragma unroll
    for (int nt = 0; nt < 9; ++nt) {
      #pragma unroll
      for (int kt = 0; kt < 4; ++kt) {
        const int fo = ((nt * 4 + kt) * 64 + lane) * 8;
        const short8 bh = *(const short8*)&shi[fo];
        const short8 bl = *(const short8*)&slo[fo];
        #pragma unroll
        for (int sub = 0; sub < 2; ++sub) {
          acc[sub][nt] = __builtin_amdgcn_mfma_f32_16x16x32_bf16(ah[sub][kt], bh, acc[sub][nt], 0, 0, 0);
          acc[sub][nt] = __builtin_amdgcn_mfma_f32_16x16x32_bf16(ah[sub][kt], bl, acc[sub][nt], 0, 0, 0);
        }
      }
    }
    #pragma unroll
    for (int sub = 0; sub < 2; ++sub) {
      const int rbase = rw + sub * 16 + kq * 4;
      #pragma unroll
      for (int nt = 0; nt < 8; ++nt) {
        const int col = nt * 16 + m;
        const float cs = (flags & GF_CSHIFT) ? cb * csum[col] : 0.f;
        const float bb = (flags & GF_BIAS) ? bias[col] : 0.f;
        #pragma unroll
        for (int r = 0; r < 4; ++r)
          C[(size_t)(rbase + r) * 128 + col] = f2bf(acc[sub][nt][r] + cs + bb);
      }
      if ((flags & GF_ALPHA) && m < 8) {
        const float cs = (flags & GF_CSHIFT) ? cb * csum[128 + m] : 0.f;
        #pragma unroll
        for (int r = 0; r < 4; ++r) {
          const float v = acc[sub][8][r] + cs;
          const int row = rbase + r;
          if (m < 4) aS[(size_t)row * 4 + m] = v;
          else       aD[(size_t)row * 4 + (m - 4)] = v;
        }
      }
    }
  }
}

// ---------------- GAT conv (bf16, mol heads=4): no max-shift ----------------------
__global__ __launch_bounds__(256) void k_conv(
    const unsigned short* __restrict__ hb, const float* __restrict__ aS,
    const float* __restrict__ aD,
    const int* __restrict__ srcs, const int* __restrict__ cnt,
    const float* __restrict__ bias, unsigned short* __restrict__ out,
    int fh_shift, int n)
{
  __shared__ int   ssh[4][2][32];
  __shared__ float wsh[4][2][32][4];
  const int wv = threadIdx.x >> 6;
  const int lane = threadIdx.x & 63;
  const int hf = lane >> 5;
  const int l  = lane & 31;
  const int i = blockIdx.x * 8 + wv * 2 + hf;
  const bool iok = i < n;
  const int ipad = iok ? i : 0;
  const int c0 = l * 4;
  const int hd = c0 >> fh_shift;

  int deg = 0;
  if (iok) { deg = cnt[i]; if (deg > MAXDEG) deg = MAXDEG; }
  const int* sp = srcs + (size_t)ipad * MAXDEG;

  const bool valid = l < deg;
  int s = ipad;
  if (valid) s = sp[l];

  f32x4 ad4 = f32x4{0.f, 0.f, 0.f, 0.f}, asi = f32x4{0.f, 0.f, 0.f, 0.f};
  if (iok) {
    ad4 = *(const f32x4*)(aD + (size_t)i * 4);
    asi = *(const f32x4*)(aS + (size_t)i * 4);
  }
  f32x4 as4 = f32x4{0.f, 0.f, 0.f, 0.f};
  if (valid) as4 = *(const f32x4*)(aS + (size_t)s * 4);

  // softmax without max-shift (values bounded; exact up to rounding)
  f32x4 w, z, wsf;
  #pragma unroll
  for (int hh = 0; hh < 4; ++hh) {
    w[hh] = valid ? __expf(lrelu(as4[hh] + ad4[hh])) : 0.f;
    z[hh] = w[hh];
  }
  #pragma unroll
  for (int o = 16; o; o >>= 1) {
    #pragma unroll
    for (int hh = 0; hh < 4; ++hh) z[hh] += __shfl_xor(z[hh], o, 32);
  }
  #pragma unroll
  for (int hh = 0; hh < 4; ++hh) {
    wsf[hh] = __expf(lrelu(asi[hh] + ad4[hh]));
    z[hh] += wsf[hh];
  }

  int dtot = (deg + 3) & ~3;
  const int dmax = max(dtot, __shfl_xor(dtot, 32));
  if (l < dmax) {
    ssh[wv][hf][l] = valid ? s : ipad;
    f32x4 wst = f32x4{0.f, 0.f, 0.f, 0.f};
    if (valid) wst = w;
    *(f32x4*)wsh[wv][hf][l] = wst;
  }

  f32x4 acc = f32x4{0.f, 0.f, 0.f, 0.f};
  {
    us4 u = {0, 0, 0, 0};
    if (iok) u = *(const us4*)(hb + (size_t)i * 128 + c0);
    const float ws = wsf[hd];
    #pragma unroll
    for (int q = 0; q < 4; ++q) acc[q] = ws * bf2f(u[q]);
  }
  for (int j0 = 0; j0 < dmax; j0 += 4) {
    const int s0 = ssh[wv][hf][j0],     s1 = ssh[wv][hf][j0 + 1];
    const int s2 = ssh[wv][hf][j0 + 2], s3 = ssh[wv][hf][j0 + 3];
    const float w0 = wsh[wv][hf][j0][hd],     w1 = wsh[wv][hf][j0 + 1][hd];
    const float w2 = wsh[wv][hf][j0 + 2][hd], w3 = wsh[wv][hf][j0 + 3][hd];
    const us4 u0 = *(const us4*)(hb + (size_t)s0 * 128 + c0);
    const us4 u1 = *(const us4*)(hb + (size_t)s1 * 128 + c0);
    const us4 u2 = *(const us4*)(hb + (size_t)s2 * 128 + c0);
    const us4 u3 = *(const us4*)(hb + (size_t)s3 * 128 + c0);
    #pragma unroll
    for (int q = 0; q < 4; ++q)
      acc[q] += w0 * bf2f(u0[q]) + w1 * bf2f(u1[q]) + w2 * bf2f(u2[q]) + w3 * bf2f(u3[q]);
  }

  if (!iok) return;
  const float inv = 1.f / (z[hd] + 1e-16f);
  const f32x4 bb = *(const f32x4*)(bias + c0);
  unsigned short* op = out + (size_t)i * 128 + c0;
  us4 res;
  #pragma unroll
  for (int q = 0; q < 4; ++q) res[q] = f2bf(acc[q] * inv + bb[q]);
  *(us4*)op = res;
}

// ---------------- fused 2-relation GAT conv (bf16, heads=2) -----------------------
// R12-proven per-rel staging protocol unchanged; NEW: both rels staged first, then
// ONE fused gather loop with wave-uniform guards -> 8 independent row loads in
// flight (was 2 serial 4-deep loops).
__global__ __launch_bounds__(256) void k_conv2(
    const unsigned short* __restrict__ hcp, const unsigned short* __restrict__ hdp,
    const float* __restrict__ aSc, const float* __restrict__ aDc,
    const float* __restrict__ aSd, const float* __restrict__ aDd,
    const int* __restrict__ srcs_c, const int* __restrict__ cnt_c,
    const int* __restrict__ srcs_d, const int* __restrict__ cnt_d,
    const float* __restrict__ bias_c, const float* __restrict__ bias_d,
    unsigned short* __restrict__ out, int n)
{
  __shared__ int   ssh[4][2][2][32];        // [wave][rel][half][slot]
  __shared__ float wsh[4][2][2][32][2];
  const int wv = threadIdx.x >> 6;
  const int lane = threadIdx.x & 63;
  const int hf = lane >> 5;
  const int l  = lane & 31;
  const int i = blockIdx.x * 8 + wv * 2 + hf;
  const bool iok = i < n;
  const int ipad = iok ? i : 0;
  const int c0 = l * 4;
  const int hd = c0 >> 6;                   // heads=2

  const unsigned short* hA[2] = {hcp, hdp};
  const float* aSA[2]  = {aSc, aSd};
  const float* aDA[2]  = {aDc, aDd};
  const int*   spA[2]  = {srcs_c, srcs_d};
  const int*   cntA[2] = {cnt_c, cnt_d};

  // ---- hoisted loads: both relations' chains issued together ----
  int deg[2]; bool valid[2]; int s[2];
  float2 ad2[2], asi2[2], as2[2];
  #pragma unroll
  for (int r = 0; r < 2; ++r) {
    deg[r] = 0;
    if (iok) { int d = cntA[r][i]; deg[r] = d > MAXDEG ? MAXDEG : d; }
  }
  #pragma unroll
  for (int r = 0; r < 2; ++r) {
    const int* sp = spA[r] + (size_t)ipad * MAXDEG;
    valid[r] = l < deg[r];
    s[r] = valid[r] ? sp[l] : ipad;
  }
  #pragma unroll
  for (int r = 0; r < 2; ++r) {
    ad2[r] = float2{0.f, 0.f};
    asi2[r] = float2{0.f, 0.f};
    if (iok) {
      ad2[r] = *(const float2*)(aDA[r] + (size_t)i * 4);
      asi2[r] = *(const float2*)(aSA[r] + (size_t)i * 4);
    }
  }
  #pragma unroll
  for (int r = 0; r < 2; ++r) {
    as2[r] = float2{0.f, 0.f};
    if (valid[r]) as2[r] = *(const float2*)(aSA[r] + (size_t)s[r] * 4);
  }

  // ---- interleaved 2-head softmax, no max-shift ----
  float w0_[2], w1_[2], z0_[2], z1_[2], wsf0_[2], wsf1_[2];
  #pragma unroll
  for (int r = 0; r < 2; ++r) {
    w0_[r] = valid[r] ? __expf(lrelu(as2[r].x + ad2[r].x)) : 0.f;
    w1_[r] = valid[r] ? __expf(lrelu(as2[r].y + ad2[r].y)) : 0.f;
    z0_[r] = w0_[r]; z1_[r] = w1_[r];
  }
  #pragma unroll
  for (int o = 16; o; o >>= 1)
    #pragma unroll
    for (int r = 0; r < 2; ++r) {
      z0_[r] += __shfl_xor(z0_[r], o, 32);
      z1_[r] += __shfl_xor(z1_[r], o, 32);
    }
  #pragma unroll
  for (int r = 0; r < 2; ++r) {
    wsf0_[r] = __expf(lrelu(asi2[r].x + ad2[r].x));
    wsf1_[r] = __expf(lrelu(asi2[r].y + ad2[r].y));
    z0_[r] += wsf0_[r];
    z1_[r] += wsf1_[r];
  }
  float i0_[2], i1_[2];
  #pragma unroll
  for (int r = 0; r < 2; ++r) {
    i0_[r] = 1.f / (z0_[r] + 1e-16f);
    i1_[r] = 1.f / (z1_[r] + 1e-16f);
  }

  // ---- stage BOTH relations (protocol per rel unchanged from R12) ----
  int dmaxA[2];
  #pragma unroll
  for (int rel = 0; rel < 2; ++rel) {
    int dtot = (deg[rel] + 3) & ~3;
    dmaxA[rel] = max(dtot, __shfl_xor(dtot, 32));
    if (l < dmaxA[rel]) {
      ssh[wv][rel][hf][l] = valid[rel] ? s[rel] : ipad;
      float2 wst = float2{0.f, 0.f};
      if (valid[rel]) wst = float2{w0_[rel] * i0_[rel], w1_[rel] * i1_[rel]};
      *(float2*)wsh[wv][rel][hf][l] = wst;
    }
  }

  // ---- self rows (2 independent loads) ----
  f32x4 acc = f32x4{0.f, 0.f, 0.f, 0.f};
  {
    us4 uc = {0, 0, 0, 0}, ud = {0, 0, 0, 0};
    if (iok) {
      uc = *(const us4*)(hcp + (size_t)i * 128 + c0);
      ud = *(const us4*)(hdp + (size_t)i * 128 + c0);
    }
    const float wc = (hd == 0) ? wsf0_[0] * i0_[0] : wsf1_[0] * i1_[0];
    const float wd = (hd == 0) ? wsf0_[1] * i0_[1] : wsf1_[1] * i1_[1];
    #pragma unroll
    for (int q = 0; q < 4; ++q) acc[q] = wc * bf2f(uc[q]) + wd * bf2f(ud[q]);
  }

  // ---- fused gather: both relations per iteration, 8 loads in flight ----
  const int dmaxM = max(dmaxA[0], dmaxA[1]);
  for (int j0 = 0; j0 < dmaxM; j0 += 4) {
    const bool g0 = j0 < dmaxA[0];   // wave-uniform
    const bool g1 = j0 < dmaxA[1];
    us4 u0a = {0,0,0,0}, u1a = {0,0,0,0}, u2a = {0,0,0,0}, u3a = {0,0,0,0};
    us4 u0b = {0,0,0,0}, u1b = {0,0,0,0}, u2b = {0,0,0,0}, u3b = {0,0,0,0};
    float wa0 = 0.f, wa1 = 0.f, wa2 = 0.f, wa3 = 0.f;
    float wb0 = 0.f, wb1 = 0.f, wb2 = 0.f, wb3 = 0.f;
    if (g0) {
      const int s0 = ssh[wv][0][hf][j0],     s1 = ssh[wv][0][hf][j0 + 1];
      const int s2 = ssh[wv][0][hf][j0 + 2], s3 = ssh[wv][0][hf][j0 + 3];
      wa0 = wsh[wv][0][hf][j0][hd];     wa1 = wsh[wv][0][hf][j0 + 1][hd];
      wa2 = wsh[wv][0][hf][j0 + 2][hd]; wa3 = wsh[wv][0][hf][j0 + 3][hd];
      u0a = *(const us4*)(hcp + (size_t)s0 * 128 + c0);
      u1a = *(const us4*)(hcp + (size_t)s1 * 128 + c0);
      u2a = *(const us4*)(hcp + (size_t)s2 * 128 + c0);
      u3a = *(const us4*)(hcp + (size_t)s3 * 128 + c0);
    }
    if (g1) {
      const int s0 = ssh[wv][1][hf][j0],     s1 = ssh[wv][1][hf][j0 + 1];
      const int s2 = ssh[wv][1][hf][j0 + 2], s3 = ssh[wv][1][hf][j0 + 3];
      wb0 = wsh[wv][1][hf][j0][hd];     wb1 = wsh[wv][1][hf][j0 + 1][hd];
      wb2 = wsh[wv][1][hf][j0 + 2][hd]; wb3 = wsh[wv][1][hf][j0 + 3][hd];
      u0b = *(const us4*)(hdp + (size_t)s0 * 128 + c0);
      u1b = *(const us4*)(hdp + (size_t)s1 * 128 + c0);
      u2b = *(const us4*)(hdp + (size_t)s2 * 128 + c0);
      u3b = *(const us4*)(hdp + (size_t)s3 * 128 + c0);
    }
    #pragma unroll
    for (int q = 0; q < 4; ++q) {
      acc[q] += wa0 * bf2f(u0a[q]) + wa1 * bf2f(u1a[q]) + wa2 * bf2f(u2a[q]) + wa3 * bf2f(u3a[q]);
      acc[q] += wb0 * bf2f(u0b[q]) + wb1 * bf2f(u1b[q]) + wb2 * bf2f(u2b[q]) + wb3 * bf2f(u3b[q]);
    }
  }

  if (!iok) return;
  const f32x4 bbc = *(const f32x4*)(bias_c + c0);
  const f32x4 bbd = *(const f32x4*)(bias_d + c0);
  unsigned short* op = out + (size_t)i * 128 + c0;
  const us4 cu = *(const us4*)op;
  us4 res;
  #pragma unroll
  for (int q = 0; q < 4; ++q)
    res[q] = f2bf(fmaxf(bf2f(cu[q]) + acc[q] + bbc[q] + bbd[q], 0.f));
  *(us4*)op = res;
}

// ---------------- output heads (bf16 h2) ----------------
__global__ __launch_bounds__(256) void k_head(
    const unsigned short* __restrict__ h2, const float* __restrict__ Wy,
    const float* __restrict__ by,
    const float* __restrict__ Wa, const float* __restrict__ ba,
    float* __restrict__ out, int n)
{
  const int r = blockIdx.x * 4 + (threadIdx.x >> 6);
  const int L = threadIdx.x & 63;
  if (r >= n) return;
  const float a = bf2f(h2[(size_t)r * 128 + L]);
  const float b = bf2f(h2[(size_t)r * 128 + 64 + L]);
  float py = a * Wy[L] + b * Wy[64 + L];
  float pa = a * Wa[L] + b * Wa[64 + L];
  #pragma unroll
  for (int o = 32; o; o >>= 1) { py += __shfl_down(py, o); pa += __shfl_down(pa, o); }
  if (L == 0) {
    out[(size_t)r * 2]     = py + by[0];
    out[(size_t)r * 2 + 1] = pa + ba[0];
  }
}

extern "C" void kernel_launch(void* const* d_in, const int* in_sizes, int n_in,
                              void* d_out, int out_size, void* d_ws, size_t ws_size,
                              hipStream_t stream) {
  const int N = in_sizes[0] / 128;
  const int E = in_sizes[2] / 2;
  const int npad = (N + 127) & ~127;

  const float* x       = (const float*)d_in[0];
  const float* pos     = (const float*)d_in[1];
  const int*   ei_chem = (const int*)d_in[2];
  const int*   ei_cond = (const int*)d_in[3];
  const int*   ei_mol  = (const int*)d_in[4];
  const float* bp = (const float*)d_in[6];
  const float* Wy = (const float*)d_in[35];
  const float* by = (const float*)d_in[36];
  const float* Wa = (const float*)d_in[37];
  const float* ba = (const float*)d_in[38];

  char* ws = (char*)d_ws;
  size_t off = 0;
  auto alloc = [&](size_t bytes) -> void* {
    void* p = ws + off; off += (bytes + 255) & ~(size_t)255; return p;
  };
  const size_t HBH = (size_t)npad * 128 * sizeof(unsigned short);
  unsigned short* H0b  = (unsigned short*)alloc(HBH);
  unsigned short* ACCb = (unsigned short*)alloc(HBH);
  unsigned short* HRb  = (unsigned short*)alloc(HBH);
  unsigned short* HRb2 = (unsigned short*)alloc(HBH);
  int* SRC[3];
  for (int r = 0; r < 3; ++r) SRC[r] = (int*)alloc((size_t)N * MAXDEG * sizeof(int));
  int*   CUR  = (int*)alloc((size_t)3 * N * sizeof(int));
  float* GSUM = (float*)alloc(256);
  float* AS   = (float*)alloc((size_t)npad * 4 * sizeof(float));
  float* AD   = (float*)alloc((size_t)npad * 4 * sizeof(float));
  float* ASd  = (float*)alloc((size_t)npad * 4 * sizeof(float));
  float* ADd  = (float*)alloc((size_t)npad * 4 * sizeof(float));

  // prepped weight images
  PrepArgs pa{};
  const int widx[9] = {5, 7, 11, 15, 19, 21, 25, 29, 33};
  const int fhs[9]  = {0, 64, 64, 32, 0, 64, 64, 32, 0};
  unsigned short *WHI[9], *WLO[9];
  float* CSUM[9];
  for (int s = 0; s < 9; ++s) {
    WHI[s]  = (unsigned short*)alloc(NFRAG * sizeof(unsigned short));
    WLO[s]  = (unsigned short*)alloc(NFRAG * sizeof(unsigned short));
    CSUM[s] = (float*)alloc(144 * sizeof(float));
    pa.W[s] = (const float*)d_in[widx[s]];
    pa.fh[s] = fhs[s];
    pa.as_[s] = fhs[s] ? (const float*)d_in[widx[s] + 1] : nullptr;
    pa.ad_[s] = fhs[s] ? (const float*)d_in[widx[s] + 2] : nullptr;
    pa.hi[s] = WHI[s]; pa.lo[s] = WLO[s]; pa.csum[s] = CSUM[s];
  }

  hipMemsetAsync(CUR, 0, (size_t)3 * N * sizeof(int), stream);
  hipMemsetAsync(GSUM, 0, sizeof(float), stream);

  k_scatter3<<<(3 * E + 255) / 256, 256, 0, stream>>>(ei_chem, ei_cond, ei_mol,
                                                      CUR, SRC[0], SRC[1], SRC[2],
                                                      pos, GSUM, E, N);
  k_prep<<<9, 256, 0, stream>>>(pa);

  const int GG = 512;
  const float gscale = 0.1f / (float)E;
  const int cgrid = (N + 7) / 8;

  // h0 = x @ Wp + bp   (fp32-A split path, bf16 out)
  k_gmm<<<GG, 256, 0, stream>>>(x, WHI[0], WLO[0], CSUM[0], bp, H0b,
                                nullptr, nullptr, nullptr, 0.f, N, npad, GF_BIAS);

  auto layer = [&](const unsigned short* Hin, unsigned short* Acc, int base, int s0) {
    const float* bc = (const float*)d_in[base + 3];
    const float* bd = (const float*)d_in[base + 7];
    const float* bm = (const float*)d_in[base + 11];
    const float* bl = (const float*)d_in[base + 13];
    // EQGAT (mol, heads=4): bf16-A GEMM + alpha + cshift; conv writes Acc; Wl in-place
    k_gmmb<<<GG, 256, 0, stream>>>(Hin, WHI[s0+2], WLO[s0+2], CSUM[s0+2], nullptr,
                                   HRb, AS, AD, GSUM, gscale, N, npad,
                                   GF_CSHIFT | GF_ALPHA);
    k_conv<<<cgrid, 256, 0, stream>>>(HRb, AS, AD, SRC[2], CUR + 2*N, bm, Acc, 5, N);
    k_gmmb<<<GG, 256, 0, stream>>>(Acc, WHI[s0+3], WLO[s0+3], CSUM[s0+3], bl, Acc,
                                   nullptr, nullptr, nullptr, 0.f, N, npad, GF_BIAS);
    // chem -> HRb (+AS/AD), cond -> HRb2 (+ASd/ADd), fused conv with relu
    k_gmmb<<<GG, 256, 0, stream>>>(Hin, WHI[s0+0], WLO[s0+0], CSUM[s0+0], nullptr,
                                   HRb, AS, AD, nullptr, 0.f, N, npad, GF_ALPHA);
    k_gmmb<<<GG, 256, 0, stream>>>(Hin, WHI[s0+1], WLO[s0+1], CSUM[s0+1], nullptr,
                                   HRb2, ASd, ADd, nullptr, 0.f, N, npad, GF_ALPHA);
    k_conv2<<<cgrid, 256, 0, stream>>>(HRb, HRb2, AS, AD, ASd, ADd,
                                       SRC[0], CUR + 0*N, SRC[1], CUR + 1*N,
                                       bc, bd, Acc, N);
  };

  layer(H0b, ACCb, 7, 1);    // h1 in ACCb
  layer(ACCb, H0b, 21, 5);   // h2 in H0b

  k_head<<<(N + 3) / 4, 256, 0, stream>>>(H0b, Wy, by, Wa, ba, (float*)d_out, N);
}

// Round 15
// 621.576 us; speedup vs baseline: 1.2406x; 1.0539x over previous
//
#include <hip/hip_runtime.h>
#include <math.h>

typedef short short8 __attribute__((ext_vector_type(8)));
typedef float f32x4 __attribute__((ext_vector_type(4)));
typedef unsigned short us4 __attribute__((ext_vector_type(4)));

#define MAXDEG 32
#define GF_BIAS   1
#define GF_CSHIFT 2
#define GF_ALPHA  4
#define NFRAG 18432   // 9 nt-tiles * 4 kt * 64 lanes * 8 bf16

__device__ __forceinline__ unsigned short f2bf(float f) {  // RNE f32->bf16
  unsigned u = __float_as_uint(f);
  u += 0x7FFF + ((u >> 16) & 1);
  return (unsigned short)(u >> 16);
}
__device__ __forceinline__ float bf2f(unsigned short s) { return __uint_as_float(((unsigned)s) << 16); }
__device__ __forceinline__ float lrelu(float v) { return v > 0.f ? v : 0.2f * v; }

// ---------------- CSR slot-scatter (3 relations), 1 edge/thread, NO geo ------------
// R4-proven 53us form. Geo fusion (R5-R14) measured +20us: rel-2 dependent chain +
// per-block barrier/reduce tax. Un-fused.
__global__ __launch_bounds__(256) void k_scatter3(
    const int* __restrict__ ei0, const int* __restrict__ ei1, const int* __restrict__ ei2,
    int* __restrict__ cur,
    int* __restrict__ s0, int* __restrict__ s1, int* __restrict__ s2,
    int E, int N) {
  const int t = blockIdx.x * 256 + threadIdx.x;
  if (t >= 3 * E) return;
  int rel, e;
  if (t < E)          { rel = 0; e = t; }
  else if (t < 2 * E) { rel = 1; e = t - E; }
  else                { rel = 2; e = t - 2 * E; }
  const int* ei = (rel == 0) ? ei0 : (rel == 1) ? ei1 : ei2;
  int* srcs     = (rel == 0) ? s0  : (rel == 1) ? s1  : s2;
  const int r = ei[e];
  const int c = ei[E + e];
  const int slot = atomicAdd(&cur[rel * N + c], 1);
  if (slot < MAXDEG) srcs[(size_t)c * MAXDEG + slot] = r;
}

// ---------------- geo distance sum (separate; grid-stride, 1 atomic/block) ---------
__global__ __launch_bounds__(256) void k_geo(const float* __restrict__ pos,
                                             const int* __restrict__ ei,
                                             float* gsum, int E) {
  __shared__ float part[4];
  float d = 0.f;
  for (int e = blockIdx.x * 256 + threadIdx.x; e < E; e += gridDim.x * 256) {
    const int r = ei[e], c = ei[E + e];
    const float dx = pos[3*r]   - pos[3*c];
    const float dy = pos[3*r+1] - pos[3*c+1];
    const float dz = pos[3*r+2] - pos[3*c+2];
    d += sqrtf(dx*dx + dy*dy + dz*dz);
  }
  #pragma unroll
  for (int o = 32; o; o >>= 1) d += __shfl_down(d, o);
  if ((threadIdx.x & 63) == 0) part[threadIdx.x >> 6] = d;
  __syncthreads();
  if (threadIdx.x == 0) atomicAdd(gsum, part[0] + part[1] + part[2] + part[3]);
}

// ---------------- weight prep: bf16 hi/lo fragment images + alpha cols + colsums ----
struct PrepArgs {
  const float* W[9];
  const float* as_[9];
  const float* ad_[9];
  unsigned short* hi[9];
  unsigned short* lo[9];
  float* csum[9];
  int fh[9];   // 0 = no alpha cols
};

__global__ __launch_bounds__(256) void k_prep(PrepArgs p) {
  const int s = blockIdx.x;
  const int t = threadIdx.x;
  const float* W = p.W[s];
  const int fh = p.fh[s];
  __shared__ float Ws[128 * 129];
  __shared__ float alpha[128 * 8];
  {
    const f32x4* src = (const f32x4*)W;
    for (int i = t; i < 4096; i += 256) {     // 16384 floats, coalesced
      const f32x4 v = src[i];
      const int row = i >> 5;
      const int col = (i & 31) * 4;
      float* dst = &Ws[row * 129 + col];
      dst[0] = v[0]; dst[1] = v[1]; dst[2] = v[2]; dst[3] = v[3];
    }
  }
  __syncthreads();
  if (t < 128) {
    #pragma unroll
    for (int a = 0; a < 8; ++a) alpha[t * 8 + a] = 0.f;
    if (fh) {
      const int nh = 128 / fh;
      for (int h = 0; h < nh; ++h) {
        float s1 = 0.f, s2 = 0.f;
        for (int c = 0; c < fh; ++c) {
          const float w = Ws[t * 129 + h * fh + c];
          s1 += w * p.as_[s][h * fh + c];
          s2 += w * p.ad_[s][h * fh + c];
        }
        alpha[t * 8 + h] = s1;
        alpha[t * 8 + 4 + h] = s2;
      }
    }
  }
  __syncthreads();
  for (int idx = t; idx < NFRAG; idx += 256) {
    const int j = idx & 7, lane = (idx >> 3) & 63, kt = (idx >> 9) & 3, nt = idx >> 11;
    const int k = kt * 32 + (lane >> 4) * 8 + j;
    const int col = nt * 16 + (lane & 15);
    float w;
    if (col < 128) w = Ws[k * 129 + col];
    else if (col < 136) w = alpha[k * 8 + (col - 128)];
    else w = 0.f;
    const unsigned short h = f2bf(w);
    p.hi[s][idx] = h;
    p.lo[s][idx] = f2bf(w - bf2f(h));
  }
  if (t < 136) {
    float cs = 0.f;
    if (t < 128) for (int k = 0; k < 128; ++k) cs += Ws[k * 129 + t];
    else         for (int k = 0; k < 128; ++k) cs += alpha[k * 8 + (t - 128)];
    p.csum[s][t] = cs;
  }
}

// ---------------- split-bf16 MFMA GEMM, fp32 A (GEMM0 only): C bf16 ---------------
__global__ __launch_bounds__(256, 2) void k_gmm(
    const float* __restrict__ A, const unsigned short* __restrict__ Whi,
    const unsigned short* __restrict__ Wlo, const float* __restrict__ csum,
    const float* __restrict__ bias, unsigned short* __restrict__ C,
    float* __restrict__ aS, float* __restrict__ aD,
    const float* __restrict__ gsum, float gscale,
    int n, int npad, int flags)
{
  __shared__ unsigned short shi[NFRAG];
  __shared__ unsigned short slo[NFRAG];
  {
    const f32x4* srch = (const f32x4*)Whi;
    const f32x4* srcl = (const f32x4*)Wlo;
    f32x4* dsth = (f32x4*)shi;
    f32x4* dstl = (f32x4*)slo;
    for (int i = threadIdx.x; i < NFRAG / 8; i += 256) { dsth[i] = srch[i]; dstl[i] = srcl[i]; }
  }
  __syncthreads();

  const int wave = threadIdx.x >> 6, lane = threadIdx.x & 63;
  const int m = lane & 15, kq = lane >> 4;
  const float cb = (flags & GF_CSHIFT) ? gscale * gsum[0] : 0.f;

  for (int rb = blockIdx.x * 128; rb < npad; rb += gridDim.x * 128) {
    const int rw = rb + wave * 32;
    short8 ah[2][4], al[2][4];
    #pragma unroll
    for (int sub = 0; sub < 2; ++sub) {
      const int row = rw + sub * 16 + m;
      const bool ok = row < n;
      const float* ap = A + (size_t)row * 128 + kq * 8;
      #pragma unroll
      for (int kt = 0; kt < 4; ++kt) {
        f32x4 x0 = {0.f, 0.f, 0.f, 0.f}, x1 = {0.f, 0.f, 0.f, 0.f};
        if (ok) { x0 = *(const f32x4*)(ap + kt * 32); x1 = *(const f32x4*)(ap + kt * 32 + 4); }
        #pragma unroll
        for (int j = 0; j < 4; ++j) {
          unsigned short h0 = f2bf(x0[j]);
          ah[sub][kt][j] = (short)h0;
          al[sub][kt][j] = (short)f2bf(x0[j] - bf2f(h0));
          unsigned short h1 = f2bf(x1[j]);
          ah[sub][kt][4 + j] = (short)h1;
          al[sub][kt][4 + j] = (short)f2bf(x1[j] - bf2f(h1));
        }
      }
    }
    f32x4 acc[2][9];
    #pragma unroll
    for (int sub = 0; sub < 2; ++sub)
      #pragma unroll
      for (int nt = 0; nt < 9; ++nt) acc[sub][nt] = f32x4{0.f, 0.f, 0.f, 0.f};

    #pragma unroll
    for (int nt = 0; nt < 9; ++nt) {
      #pragma unroll
      for (int kt = 0; kt < 4; ++kt) {
        const int fo = ((nt * 4 + kt) * 64 + lane) * 8;
        const short8 bh = *(const short8*)&shi[fo];
        const short8 bl = *(const short8*)&slo[fo];
        #pragma unroll
        for (int sub = 0; sub < 2; ++sub) {
          acc[sub][nt] = __builtin_amdgcn_mfma_f32_16x16x32_bf16(ah[sub][kt], bh, acc[sub][nt], 0, 0, 0);
          acc[sub][nt] = __builtin_amdgcn_mfma_f32_16x16x32_bf16(al[sub][kt], bh, acc[sub][nt], 0, 0, 0);
          acc[sub][nt] = __builtin_amdgcn_mfma_f32_16x16x32_bf16(ah[sub][kt], bl, acc[sub][nt], 0, 0, 0);
        }
      }
    }
    #pragma unroll
    for (int sub = 0; sub < 2; ++sub) {
      const int rbase = rw + sub * 16 + kq * 4;
      #pragma unroll
      for (int nt = 0; nt < 8; ++nt) {
        const int col = nt * 16 + m;
        const float cs = (flags & GF_CSHIFT) ? cb * csum[col] : 0.f;
        const float bb = (flags & GF_BIAS) ? bias[col] : 0.f;
        #pragma unroll
        for (int r = 0; r < 4; ++r)
          C[(size_t)(rbase + r) * 128 + col] = f2bf(acc[sub][nt][r] + cs + bb);
      }
      if ((flags & GF_ALPHA) && m < 8) {
        const float cs = (flags & GF_CSHIFT) ? cb * csum[128 + m] : 0.f;
        #pragma unroll
        for (int r = 0; r < 4; ++r) {
          const float v = acc[sub][8][r] + cs;
          const int row = rbase + r;
          if (m < 4) aS[(size_t)row * 4 + m] = v;
          else       aD[(size_t)row * 4 + (m - 4)] = v;
        }
      }
    }
  }
}

// ---------------- bf16-A MFMA GEMM, hi+lo W (Wl in-place GEMM) --------------------
__global__ __launch_bounds__(256, 2) void k_gmmb(
    const unsigned short* __restrict__ A, const unsigned short* __restrict__ Whi,
    const unsigned short* __restrict__ Wlo, const float* __restrict__ csum,
    const float* __restrict__ bias, unsigned short* __restrict__ C,
    float* __restrict__ aS, float* __restrict__ aD,
    const float* __restrict__ gsum, float gscale,
    int n, int npad, int flags)
{
  __shared__ unsigned short shi[NFRAG];
  __shared__ unsigned short slo[NFRAG];
  {
    const f32x4* srch = (const f32x4*)Whi;
    const f32x4* srcl = (const f32x4*)Wlo;
    f32x4* dsth = (f32x4*)shi;
    f32x4* dstl = (f32x4*)slo;
    for (int i = threadIdx.x; i < NFRAG / 8; i += 256) { dsth[i] = srch[i]; dstl[i] = srcl[i]; }
  }
  __syncthreads();

  const int wave = threadIdx.x >> 6, lane = threadIdx.x & 63;
  const int m = lane & 15, kq = lane >> 4;
  const float cb = (flags & GF_CSHIFT) ? gscale * gsum[0] : 0.f;

  for (int rb = blockIdx.x * 128; rb < npad; rb += gridDim.x * 128) {
    const int rw = rb + wave * 32;
    short8 ah[2][4];
    #pragma unroll
    for (int sub = 0; sub < 2; ++sub) {
      const int row = rw + sub * 16 + m;
      const bool ok = row < n;
      const unsigned short* ap = A + (size_t)row * 128 + kq * 8;
      #pragma unroll
      for (int kt = 0; kt < 4; ++kt) {
        if (ok) ah[sub][kt] = *(const short8*)(ap + kt * 32);
        else    ah[sub][kt] = short8{0, 0, 0, 0, 0, 0, 0, 0};
      }
    }
    f32x4 acc[2][9];
    #pragma unroll
    for (int sub = 0; sub < 2; ++sub)
      #pragma unroll
      for (int nt = 0; nt < 9; ++nt) acc[sub][nt] = f32x4{0.f, 0.f, 0.f, 0.f};

    #pragma unroll
    for (int nt = 0; nt < 9; ++nt) {
      #pragma unroll
      for (int kt = 0; kt < 4; ++kt) {
        const int fo = ((nt * 4 + kt) * 64 + lane) * 8;
        const short8 bh = *(const short8*)&shi[fo];
        const short8 bl = *(const short8*)&slo[fo];
        #pragma unroll
        for (int sub = 0; sub < 2; ++sub) {
          acc[sub][nt] = __builtin_amdgcn_mfma_f32_16x16x32_bf16(ah[sub][kt], bh, acc[sub][nt], 0, 0, 0);
          acc[sub][nt] = __builtin_amdgcn_mfma_f32_16x16x32_bf16(ah[sub][kt], bl, acc[sub][nt], 0, 0, 0);
        }
      }
    }
    #pragma unroll
    for (int sub = 0; sub < 2; ++sub) {
      const int rbase = rw + sub * 16 + kq * 4;
      #pragma unroll
      for (int nt = 0; nt < 8; ++nt) {
        const int col = nt * 16 + m;
        const float cs = (flags & GF_CSHIFT) ? cb * csum[col] : 0.f;
        const float bb = (flags & GF_BIAS) ? bias[col] : 0.f;
        #pragma unroll
        for (int r = 0; r < 4; ++r)
          C[(size_t)(rbase + r) * 128 + col] = f2bf(acc[sub][nt][r] + cs + bb);
      }
      if ((flags & GF_ALPHA) && m < 8) {
        const float cs = (flags & GF_CSHIFT) ? cb * csum[128 + m] : 0.f;
        #pragma unroll
        for (int r = 0; r < 4; ++r) {
          const float v = acc[sub][8][r] + cs;
          const int row = rbase + r;
          if (m < 4) aS[(size_t)row * 4 + m] = v;
          else       aD[(size_t)row * 4 + (m - 4)] = v;
        }
      }
    }
  }
}

// ---------------- bf16-A MFMA GEMM, hi-only W (HR-producing GEMMs) ----------------
// Half the MFMAs, half the LDS (36KB) -> 3 blocks/CU. Adds bf16 W-quantization on
// HR/alpha paths only (attenuated through softmax-weighted averaging).
__global__ __launch_bounds__(256, 3) void k_gmmh(
    const unsigned short* __restrict__ A, const unsigned short* __restrict__ Whi,
    const float* __restrict__ csum,
    unsigned short* __restrict__ C,
    float* __restrict__ aS, float* __restrict__ aD,
    const float* __restrict__ gsum, float gscale,
    int n, int npad, int flags)
{
  __shared__ unsigned short shi[NFRAG];
  {
    const f32x4* srch = (const f32x4*)Whi;
    f32x4* dsth = (f32x4*)shi;
    for (int i = threadIdx.x; i < NFRAG / 8; i += 256) dsth[i] = srch[i];
  }
  __syncthreads();

  const int wave = threadIdx.x >> 6, lane = threadIdx.x & 63;
  const int m = lane & 15, kq = lane >> 4;
  const float cb = (flags & GF_CSHIFT) ? gscale * gsum[0] : 0.f;

  for (int rb = blockIdx.x * 128; rb < npad; rb += gridDim.x * 128) {
    const int rw = rb + wave * 32;
    short8 ah[2][4];
    #pragma unroll
    for (int sub = 0; sub < 2; ++sub) {
      const int row = rw + sub * 16 + m;
      const bool ok = row < n;
      const unsigned short* ap = A + (size_t)row * 128 + kq * 8;
      #pragma unroll
      for (int kt = 0; kt < 4; ++kt) {
        if (ok) ah[sub][kt] = *(const short8*)(ap + kt * 32);
        else    ah[sub][kt] = short8{0, 0, 0, 0, 0, 0, 0, 0};
      }
    }
    f32x4 acc[2][9];
    #pragma unroll
    for (int sub = 0; sub < 2; ++sub)
      #pragma unroll
      for (int nt = 0; nt < 9; ++nt) acc[sub][nt] = f32x4{0.f, 0.f, 0.f, 0.f};

    #pragma unroll
    for (int nt = 0; nt < 9; ++nt) {
      #pragma unroll
      for (int kt = 0; kt < 4; ++kt) {
        const int fo = ((nt * 4 + kt) * 64 + lane) * 8;
        const short8 bh = *(const short8*)&shi[fo];
        #pragma unroll
        for (int sub = 0; sub < 2; ++sub)
          acc[sub][nt] = __builtin_amdgcn_mfma_f32_16x16x32_bf16(ah[sub][kt], bh, acc[sub][nt], 0, 0, 0);
      }
    }
    #pragma unroll
    for (int sub = 0; sub < 2; ++sub) {
      const int rbase = rw + sub * 16 + kq * 4;
      #pragma unroll
      for (int nt = 0; nt < 8; ++nt) {
        const int col = nt * 16 + m;
        const float cs = (flags & GF_CSHIFT) ? cb * csum[col] : 0.f;
        #pragma unroll
        for (int r = 0; r < 4; ++r)
          C[(size_t)(rbase + r) * 128 + col] = f2bf(acc[sub][nt][r] + cs);
      }
      if ((flags & GF_ALPHA) && m < 8) {
        const float cs = (flags & GF_CSHIFT) ? cb * csum[128 + m] : 0.f;
        #pragma unroll
        for (int r = 0; r < 4; ++r) {
          const float v = acc[sub][8][r] + cs;
          const int row = rbase + r;
          if (m < 4) aS[(size_t)row * 4 + m] = v;
          else       aD[(size_t)row * 4 + (m - 4)] = v;
        }
      }
    }
  }
}

// ---------------- GAT conv (bf16, mol heads=4): no max-shift ----------------------
__global__ __launch_bounds__(256) void k_conv(
    const unsigned short* __restrict__ hb, const float* __restrict__ aS,
    const float* __restrict__ aD,
    const int* __restrict__ srcs, const int* __restrict__ cnt,
    const float* __restrict__ bias, unsigned short* __restrict__ out,
    int fh_shift, int n)
{
  __shared__ int   ssh[4][2][32];
  __shared__ float wsh[4][2][32][4];
  const int wv = threadIdx.x >> 6;
  const int lane = threadIdx.x & 63;
  const int hf = lane >> 5;
  const int l  = lane & 31;
  const int i = blockIdx.x * 8 + wv * 2 + hf;
  const bool iok = i < n;
  const int ipad = iok ? i : 0;
  const int c0 = l * 4;
  const int hd = c0 >> fh_shift;

  int deg = 0;
  if (iok) { deg = cnt[i]; if (deg > MAXDEG) deg = MAXDEG; }
  const int* sp = srcs + (size_t)ipad * MAXDEG;

  const bool valid = l < deg;
  int s = ipad;
  if (valid) s = sp[l];

  f32x4 ad4 = f32x4{0.f, 0.f, 0.f, 0.f}, asi = f32x4{0.f, 0.f, 0.f, 0.f};
  if (iok) {
    ad4 = *(const f32x4*)(aD + (size_t)i * 4);
    asi = *(const f32x4*)(aS + (size_t)i * 4);
  }
  f32x4 as4 = f32x4{0.f, 0.f, 0.f, 0.f};
  if (valid) as4 = *(const f32x4*)(aS + (size_t)s * 4);

  f32x4 w, z, wsf;
  #pragma unroll
  for (int hh = 0; hh < 4; ++hh) {
    w[hh] = valid ? __expf(lrelu(as4[hh] + ad4[hh])) : 0.f;
    z[hh] = w[hh];
  }
  #pragma unroll
  for (int o = 16; o; o >>= 1) {
    #pragma unroll
    for (int hh = 0; hh < 4; ++hh) z[hh] += __shfl_xor(z[hh], o, 32);
  }
  #pragma unroll
  for (int hh = 0; hh < 4; ++hh) {
    wsf[hh] = __expf(lrelu(asi[hh] + ad4[hh]));
    z[hh] += wsf[hh];
  }

  int dtot = (deg + 3) & ~3;
  const int dmax = max(dtot, __shfl_xor(dtot, 32));
  if (l < dmax) {
    ssh[wv][hf][l] = valid ? s : ipad;
    f32x4 wst = f32x4{0.f, 0.f, 0.f, 0.f};
    if (valid) wst = w;
    *(f32x4*)wsh[wv][hf][l] = wst;
  }

  f32x4 acc = f32x4{0.f, 0.f, 0.f, 0.f};
  {
    us4 u = {0, 0, 0, 0};
    if (iok) u = *(const us4*)(hb + (size_t)i * 128 + c0);
    const float ws = wsf[hd];
    #pragma unroll
    for (int q = 0; q < 4; ++q) acc[q] = ws * bf2f(u[q]);
  }
  for (int j0 = 0; j0 < dmax; j0 += 4) {
    const int s0 = ssh[wv][hf][j0],     s1 = ssh[wv][hf][j0 + 1];
    const int s2 = ssh[wv][hf][j0 + 2], s3 = ssh[wv][hf][j0 + 3];
    const float w0 = wsh[wv][hf][j0][hd],     w1 = wsh[wv][hf][j0 + 1][hd];
    const float w2 = wsh[wv][hf][j0 + 2][hd], w3 = wsh[wv][hf][j0 + 3][hd];
    const us4 u0 = *(const us4*)(hb + (size_t)s0 * 128 + c0);
    const us4 u1 = *(const us4*)(hb + (size_t)s1 * 128 + c0);
    const us4 u2 = *(const us4*)(hb + (size_t)s2 * 128 + c0);
    const us4 u3 = *(const us4*)(hb + (size_t)s3 * 128 + c0);
    #pragma unroll
    for (int q = 0; q < 4; ++q)
      acc[q] += w0 * bf2f(u0[q]) + w1 * bf2f(u1[q]) + w2 * bf2f(u2[q]) + w3 * bf2f(u3[q]);
  }

  if (!iok) return;
  const float inv = 1.f / (z[hd] + 1e-16f);
  const f32x4 bb = *(const f32x4*)(bias + c0);
  unsigned short* op = out + (size_t)i * 128 + c0;
  us4 res;
  #pragma unroll
  for (int q = 0; q < 4; ++q) res[q] = f2bf(acc[q] * inv + bb[q]);
  *(us4*)op = res;
}

// ---------------- fused 2-relation GAT conv (bf16, heads=2), fused gather ---------
__global__ __launch_bounds__(256) void k_conv2(
    const unsigned short* __restrict__ hcp, const unsigned short* __restrict__ hdp,
    const float* __restrict__ aSc, const float* __restrict__ aDc,
    const float* __restrict__ aSd, const float* __restrict__ aDd,
    const int* __restrict__ srcs_c, const int* __restrict__ cnt_c,
    const int* __restrict__ srcs_d, const int* __restrict__ cnt_d,
    const float* __restrict__ bias_c, const float* __restrict__ bias_d,
    unsigned short* __restrict__ out, int n)
{
  __shared__ int   ssh[4][2][2][32];        // [wave][rel][half][slot]
  __shared__ float wsh[4][2][2][32][2];
  const int wv = threadIdx.x >> 6;
  const int lane = threadIdx.x & 63;
  const int hf = lane >> 5;
  const int l  = lane & 31;
  const int i = blockIdx.x * 8 + wv * 2 + hf;
  const bool iok = i < n;
  const int ipad = iok ? i : 0;
  const int c0 = l * 4;
  const int hd = c0 >> 6;                   // heads=2

  const float* aSA[2]  = {aSc, aSd};
  const float* aDA[2]  = {aDc, aDd};
  const int*   spA[2]  = {srcs_c, srcs_d};
  const int*   cntA[2] = {cnt_c, cnt_d};

  int deg[2]; bool valid[2]; int s[2];
  float2 ad2[2], asi2[2], as2[2];
  #pragma unroll
  for (int r = 0; r < 2; ++r) {
    deg[r] = 0;
    if (iok) { int d = cntA[r][i]; deg[r] = d > MAXDEG ? MAXDEG : d; }
  }
  #pragma unroll
  for (int r = 0; r < 2; ++r) {
    const int* sp = spA[r] + (size_t)ipad * MAXDEG;
    valid[r] = l < deg[r];
    s[r] = valid[r] ? sp[l] : ipad;
  }
  #pragma unroll
  for (int r = 0; r < 2; ++r) {
    ad2[r] = float2{0.f, 0.f};
    asi2[r] = float2{0.f, 0.f};
    if (iok) {
      ad2[r] = *(const float2*)(aDA[r] + (size_t)i * 4);
      asi2[r] = *(const float2*)(aSA[r] + (size_t)i * 4);
    }
  }
  #pragma unroll
  for (int r = 0; r < 2; ++r) {
    as2[r] = float2{0.f, 0.f};
    if (valid[r]) as2[r] = *(const float2*)(aSA[r] + (size_t)s[r] * 4);
  }

  float w0_[2], w1_[2], z0_[2], z1_[2], wsf0_[2], wsf1_[2];
  #pragma unroll
  for (int r = 0; r < 2; ++r) {
    w0_[r] = valid[r] ? __expf(lrelu(as2[r].x + ad2[r].x)) : 0.f;
    w1_[r] = valid[r] ? __expf(lrelu(as2[r].y + ad2[r].y)) : 0.f;
    z0_[r] = w0_[r]; z1_[r] = w1_[r];
  }
  #pragma unroll
  for (int o = 16; o; o >>= 1)
    #pragma unroll
    for (int r = 0; r < 2; ++r) {
      z0_[r] += __shfl_xor(z0_[r], o, 32);
      z1_[r] += __shfl_xor(z1_[r], o, 32);
    }
  #pragma unroll
  for (int r = 0; r < 2; ++r) {
    wsf0_[r] = __expf(lrelu(asi2[r].x + ad2[r].x));
    wsf1_[r] = __expf(lrelu(asi2[r].y + ad2[r].y));
    z0_[r] += wsf0_[r];
    z1_[r] += wsf1_[r];
  }
  float i0_[2], i1_[2];
  #pragma unroll
  for (int r = 0; r < 2; ++r) {
    i0_[r] = 1.f / (z0_[r] + 1e-16f);
    i1_[r] = 1.f / (z1_[r] + 1e-16f);
  }

  int dmaxA[2];
  #pragma unroll
  for (int rel = 0; rel < 2; ++rel) {
    int dtot = (deg[rel] + 3) & ~3;
    dmaxA[rel] = max(dtot, __shfl_xor(dtot, 32));
    if (l < dmaxA[rel]) {
      ssh[wv][rel][hf][l] = valid[rel] ? s[rel] : ipad;
      float2 wst = float2{0.f, 0.f};
      if (valid[rel]) wst = float2{w0_[rel] * i0_[rel], w1_[rel] * i1_[rel]};
      *(float2*)wsh[wv][rel][hf][l] = wst;
    }
  }

  f32x4 acc = f32x4{0.f, 0.f, 0.f, 0.f};
  {
    us4 uc = {0, 0, 0, 0}, ud = {0, 0, 0, 0};
    if (iok) {
      uc = *(const us4*)(hcp + (size_t)i * 128 + c0);
      ud = *(const us4*)(hdp + (size_t)i * 128 + c0);
    }
    const float wc = (hd == 0) ? wsf0_[0] * i0_[0] : wsf1_[0] * i1_[0];
    const float wd = (hd == 0) ? wsf0_[1] * i0_[1] : wsf1_[1] * i1_[1];
    #pragma unroll
    for (int q = 0; q < 4; ++q) acc[q] = wc * bf2f(uc[q]) + wd * bf2f(ud[q]);
  }

  const int dmaxM = max(dmaxA[0], dmaxA[1]);
  for (int j0 = 0; j0 < dmaxM; j0 += 4) {
    const bool g0 = j0 < dmaxA[0];   // wave-uniform
    const bool g1 = j0 < dmaxA[1];
    us4 u0a = {0,0,0,0}, u1a = {0,0,0,0}, u2a = {0,0,0,0}, u3a = {0,0,0,0};
    us4 u0b = {0,0,0,0}, u1b = {0,0,0,0}, u2b = {0,0,0,0}, u3b = {0,0,0,0};
    float wa0 = 0.f, wa1 = 0.f, wa2 = 0.f, wa3 = 0.f;
    float wb0 = 0.f, wb1 = 0.f, wb2 = 0.f, wb3 = 0.f;
    if (g0) {
      const int s0 = ssh[wv][0][hf][j0],     s1 = ssh[wv][0][hf][j0 + 1];
      const int s2 = ssh[wv][0][hf][j0 + 2], s3 = ssh[wv][0][hf][j0 + 3];
      wa0 = wsh[wv][0][hf][j0][hd];     wa1 = wsh[wv][0][hf][j0 + 1][hd];
      wa2 = wsh[wv][0][hf][j0 + 2][hd]; wa3 = wsh[wv][0][hf][j0 + 3][hd];
      u0a = *(const us4*)(hcp + (size_t)s0 * 128 + c0);
      u1a = *(const us4*)(hcp + (size_t)s1 * 128 + c0);
      u2a = *(const us4*)(hcp + (size_t)s2 * 128 + c0);
      u3a = *(const us4*)(hcp + (size_t)s3 * 128 + c0);
    }
    if (g1) {
      const int s0 = ssh[wv][1][hf][j0],     s1 = ssh[wv][1][hf][j0 + 1];
      const int s2 = ssh[wv][1][hf][j0 + 2], s3 = ssh[wv][1][hf][j0 + 3];
      wb0 = wsh[wv][1][hf][j0][hd];     wb1 = wsh[wv][1][hf][j0 + 1][hd];
      wb2 = wsh[wv][1][hf][j0 + 2][hd]; wb3 = wsh[wv][1][hf][j0 + 3][hd];
      u0b = *(const us4*)(hdp + (size_t)s0 * 128 + c0);
      u1b = *(const us4*)(hdp + (size_t)s1 * 128 + c0);
      u2b = *(const us4*)(hdp + (size_t)s2 * 128 + c0);
      u3b = *(const us4*)(hdp + (size_t)s3 * 128 + c0);
    }
    #pragma unroll
    for (int q = 0; q < 4; ++q) {
      acc[q] += wa0 * bf2f(u0a[q]) + wa1 * bf2f(u1a[q]) + wa2 * bf2f(u2a[q]) + wa3 * bf2f(u3a[q]);
      acc[q] += wb0 * bf2f(u0b[q]) + wb1 * bf2f(u1b[q]) + wb2 * bf2f(u2b[q]) + wb3 * bf2f(u3b[q]);
    }
  }

  if (!iok) return;
  const f32x4 bbc = *(const f32x4*)(bias_c + c0);
  const f32x4 bbd = *(const f32x4*)(bias_d + c0);
  unsigned short* op = out + (size_t)i * 128 + c0;
  const us4 cu = *(const us4*)op;
  us4 res;
  #pragma unroll
  for (int q = 0; q < 4; ++q)
    res[q] = f2bf(fmaxf(bf2f(cu[q]) + acc[q] + bbc[q] + bbd[q], 0.f));
  *(us4*)op = res;
}

// ---------------- output heads (bf16 h2) ----------------
__global__ __launch_bounds__(256) void k_head(
    const unsigned short* __restrict__ h2, const float* __restrict__ Wy,
    const float* __restrict__ by,
    const float* __restrict__ Wa, const float* __restrict__ ba,
    float* __restrict__ out, int n)
{
  const int r = blockIdx.x * 4 + (threadIdx.x >> 6);
  const int L = threadIdx.x & 63;
  if (r >= n) return;
  const float a = bf2f(h2[(size_t)r * 128 + L]);
  const float b = bf2f(h2[(size_t)r * 128 + 64 + L]);
  float py = a * Wy[L] + b * Wy[64 + L];
  float pa = a * Wa[L] + b * Wa[64 + L];
  #pragma unroll
  for (int o = 32; o; o >>= 1) { py += __shfl_down(py, o); pa += __shfl_down(pa, o); }
  if (L == 0) {
    out[(size_t)r * 2]     = py + by[0];
    out[(size_t)r * 2 + 1] = pa + ba[0];
  }
}

extern "C" void kernel_launch(void* const* d_in, const int* in_sizes, int n_in,
                              void* d_out, int out_size, void* d_ws, size_t ws_size,
                              hipStream_t stream) {
  const int N = in_sizes[0] / 128;
  const int E = in_sizes[2] / 2;
  const int npad = (N + 127) & ~127;

  const float* x       = (const float*)d_in[0];
  const float* pos     = (const float*)d_in[1];
  const int*   ei_chem = (const int*)d_in[2];
  const int*   ei_cond = (const int*)d_in[3];
  const int*   ei_mol  = (const int*)d_in[4];
  const float* bp = (const float*)d_in[6];
  const float* Wy = (const float*)d_in[35];
  const float* by = (const float*)d_in[36];
  const float* Wa = (const float*)d_in[37];
  const float* ba = (const float*)d_in[38];

  char* ws = (char*)d_ws;
  size_t off = 0;
  auto alloc = [&](size_t bytes) -> void* {
    void* p = ws + off; off += (bytes + 255) & ~(size_t)255; return p;
  };
  const size_t HBH = (size_t)npad * 128 * sizeof(unsigned short);
  unsigned short* H0b  = (unsigned short*)alloc(HBH);
  unsigned short* ACCb = (unsigned short*)alloc(HBH);
  unsigned short* HRb  = (unsigned short*)alloc(HBH);
  unsigned short* HRb2 = (unsigned short*)alloc(HBH);
  int* SRC[3];
  for (int r = 0; r < 3; ++r) SRC[r] = (int*)alloc((size_t)N * MAXDEG * sizeof(int));
  int*   CUR  = (int*)alloc((size_t)3 * N * sizeof(int));
  float* GSUM = (float*)alloc(256);
  float* AS   = (float*)alloc((size_t)npad * 4 * sizeof(float));
  float* AD   = (float*)alloc((size_t)npad * 4 * sizeof(float));
  float* ASd  = (float*)alloc((size_t)npad * 4 * sizeof(float));
  float* ADd  = (float*)alloc((size_t)npad * 4 * sizeof(float));

  // prepped weight images
  PrepArgs pa{};
  const int widx[9] = {5, 7, 11, 15, 19, 21, 25, 29, 33};
  const int fhs[9]  = {0, 64, 64, 32, 0, 64, 64, 32, 0};
  unsigned short *WHI[9], *WLO[9];
  float* CSUM[9];
  for (int s = 0; s < 9; ++s) {
    WHI[s]  = (unsigned short*)alloc(NFRAG * sizeof(unsigned short));
    WLO[s]  = (unsigned short*)alloc(NFRAG * sizeof(unsigned short));
    CSUM[s] = (float*)alloc(144 * sizeof(float));
    pa.W[s] = (const float*)d_in[widx[s]];
    pa.fh[s] = fhs[s];
    pa.as_[s] = fhs[s] ? (const float*)d_in[widx[s] + 1] : nullptr;
    pa.ad_[s] = fhs[s] ? (const float*)d_in[widx[s] + 2] : nullptr;
    pa.hi[s] = WHI[s]; pa.lo[s] = WLO[s]; pa.csum[s] = CSUM[s];
  }

  hipMemsetAsync(CUR, 0, (size_t)3 * N * sizeof(int), stream);
  hipMemsetAsync(GSUM, 0, sizeof(float), stream);

  k_scatter3<<<(3 * E + 255) / 256, 256, 0, stream>>>(ei_chem, ei_cond, ei_mol,
                                                      CUR, SRC[0], SRC[1], SRC[2], E, N);
  k_geo<<<512, 256, 0, stream>>>(pos, ei_mol, GSUM, E);
  k_prep<<<9, 256, 0, stream>>>(pa);

  const int GG = 512;
  const float gscale = 0.1f / (float)E;
  const int cgrid = (N + 7) / 8;

  // h0 = x @ Wp + bp   (fp32-A split path, bf16 out)
  k_gmm<<<GG, 256, 0, stream>>>(x, WHI[0], WLO[0], CSUM[0], bp, H0b,
                                nullptr, nullptr, nullptr, 0.f, N, npad, GF_BIAS);

  auto layer = [&](const unsigned short* Hin, unsigned short* Acc, int base, int s0) {
    const float* bc = (const float*)d_in[base + 3];
    const float* bd = (const float*)d_in[base + 7];
    const float* bm = (const float*)d_in[base + 11];
    const float* bl = (const float*)d_in[base + 13];
    // EQGAT (mol, heads=4): hi-only GEMM + alpha + cshift; conv writes Acc; Wl in-place
    k_gmmh<<<GG, 256, 0, stream>>>(Hin, WHI[s0+2], CSUM[s0+2], HRb, AS, AD,
                                   GSUM, gscale, N, npad, GF_CSHIFT | GF_ALPHA);
    k_conv<<<cgrid, 256, 0, stream>>>(HRb, AS, AD, SRC[2], CUR + 2*N, bm, Acc, 5, N);
    k_gmmb<<<GG, 256, 0, stream>>>(Acc, WHI[s0+3], WLO[s0+3], CSUM[s0+3], bl, Acc,
                                   nullptr, nullptr, nullptr, 0.f, N, npad, GF_BIAS);
    // chem -> HRb (+AS/AD), cond -> HRb2 (+ASd/ADd), fused conv with relu
    k_gmmh<<<GG, 256, 0, stream>>>(Hin, WHI[s0+0], CSUM[s0+0], HRb, AS, AD,
                                   GSUM, 0.f, N, npad, GF_ALPHA);
    k_gmmh<<<GG, 256, 0, stream>>>(Hin, WHI[s0+1], CSUM[s0+1], HRb2, ASd, ADd,
                                   GSUM, 0.f, N, npad, GF_ALPHA);
    k_conv2<<<cgrid, 256, 0, stream>>>(HRb, HRb2, AS, AD, ASd, ADd,
                                       SRC[0], CUR + 0*N, SRC[1], CUR + 1*N,
                                       bc, bd, Acc, N);
  };

  layer(H0b, ACCb, 7, 1);    // h1 in ACCb
  layer(ACCb, H0b, 21, 5);   // h2 in H0b

  k_head<<<(N + 3) / 4, 256, 0, stream>>>(H0b, Wy, by, Wa, ba, (float*)d_out, N);
}